// Round 3
// baseline (1183.738 us; speedup 1.0000x reference)
//
#include <hip/hip_runtime.h>
#include <hip/hip_bf16.h>
#include <cstdint>
#include <cstddef>

#define DMODEL 1024
#define DINNER 2048
#define NSTATE 16
#define DTRANK 64
#define BATCH 2
#define SEQ 1024
#define ROWS (BATCH*SEQ)   // 2048 token rows

typedef __attribute__((ext_vector_type(8))) short short8;
typedef __attribute__((ext_vector_type(4))) float f32x4;

__device__ __forceinline__ float bf2f(__hip_bfloat16 h){ return __bfloat162float(h); }
__device__ __forceinline__ float sigmoidf_(float x){ return 1.0f/(1.0f + __expf(-x)); }

__device__ __forceinline__ void gld16(const void* g, void* l){
  __builtin_amdgcn_global_load_lds((const __attribute__((address_space(1))) void*)g,
                                   (__attribute__((address_space(3))) void*)l, 16, 0, 0);
}

// ---------------------------------------------------------------------------
// dtype sniffer (validated R2: picked f32 on f32 data). bf16 storage -> ~100%
// of halves have bf16-exponent in [0x70,0x86] for N(0,1); f32 storage -> ~55%.
// ---------------------------------------------------------------------------
__global__ void sniff_k(const unsigned short* __restrict__ xu, int* __restrict__ flag)
{
  int t = threadIdx.x;           // 64 threads
  int cnt = 0;
  for (int i = t; i < 1024; i += 64) {
    unsigned short u = xu[i];
    int e = (u >> 7) & 0xFF;
    if (e >= 0x70 && e <= 0x86) cnt++;
  }
  for (int o = 32; o; o >>= 1) cnt += __shfl_down(cnt, o);
  if (t == 0) *flag = (cnt >= 768) ? 0 : 1;
}

// canonicalize one tensor: read per flag, write bf16 and/or f32 copies
__global__ __launch_bounds__(256)
void convert_k(const void* __restrict__ src, int n, const int* __restrict__ flag,
               __hip_bfloat16* __restrict__ dB, float* __restrict__ dF)
{
  int i = blockIdx.x * 256 + threadIdx.x;
  if (i >= n) return;
  float v;
  if (*flag) v = ((const float*)src)[i];
  else       v = bf2f(((const __hip_bfloat16*)src)[i]);
  if (dB) dB[i] = __float2bfloat16(v);
  if (dF) dF[i] = v;
}

// ---------------------------------------------------------------------------
// NT GEMM: C[M,N] = A[M,K] (bf16, lda=K) x W[N,K]^T (bf16, ldw=K)
// 128x128 tile, BK=32, 256 threads (4 waves 2x2), mfma_f32_16x16x32_bf16.
// EPI: 0 = store f32 (ldC)                          (out_proj -> f32 d_out)
//      2 = x_dbl split: f32 cols<96 + bf16 cols<64 into aux (dt)
//      3 = softplus(acc + biasF[col]) -> f32 (ldC)  (delta)
//      4 = in_proj split: col<2048 -> bf16 xi (outH); col>=2048 -> silu -> f32 outF
// ---------------------------------------------------------------------------
template<int EPI>
__global__ __launch_bounds__(256)
void gemm_bt(const __hip_bfloat16* __restrict__ A,
             const __hip_bfloat16* __restrict__ W,
             int M, int N, int K, int ldC,
             float* __restrict__ outF,
             __hip_bfloat16* __restrict__ outH,
             const float* __restrict__ biasF,
             __hip_bfloat16* __restrict__ aux)
{
  __shared__ alignas(16) __hip_bfloat16 As[128*32];
  __shared__ alignas(16) __hip_bfloat16 Ws[128*32];
  const int tid  = threadIdx.x;
  const int lane = tid & 63;
  const int wave = tid >> 6;
  const int wm = wave & 1, wn = wave >> 1;
  const int row0 = blockIdx.y * 128;
  const int col0 = blockIdx.x * 128;

  f32x4 acc[4][4] = {};

  const int e0 = tid, e1 = tid + 256;   // 16B-granule ids (512 per tile)

  for (int k0 = 0; k0 < K; k0 += 32) {
    { // A tile: granule e covers row e/4, k-seg e%4 (8 bf16); LDS offset e*16
      int r = e0 >> 2, ks = e0 & 3;
      gld16(A + (size_t)(row0 + r) * K + k0 + ks*8, (char*)As + (size_t)e0*16);
      r = e1 >> 2; ks = e1 & 3;
      gld16(A + (size_t)(row0 + r) * K + k0 + ks*8, (char*)As + (size_t)e1*16);
    }
    { // W tile (clamp row for N<128: keeps addresses in-bounds; masked at store)
      int r = e0 >> 2, ks = e0 & 3;
      int rw = col0 + r; if (rw > N-1) rw = N-1;
      gld16(W + (size_t)rw * K + k0 + ks*8, (char*)Ws + (size_t)e0*16);
      r = e1 >> 2; ks = e1 & 3;
      rw = col0 + r; if (rw > N-1) rw = N-1;
      gld16(W + (size_t)rw * K + k0 + ks*8, (char*)Ws + (size_t)e1*16);
    }
    __syncthreads();   // compiler drains vmcnt before s_barrier

    const char* Ab = (const char*)As + ((wm*64 + (lane & 15)) * 64) + ((lane >> 4) * 16);
    const char* Wb = (const char*)Ws + ((wn*64 + (lane & 15)) * 64) + ((lane >> 4) * 16);
    short8 af[4], wf[4];
#pragma unroll
    for (int i = 0; i < 4; ++i) af[i] = *(const short8*)(Ab + i*16*64);
#pragma unroll
    for (int i = 0; i < 4; ++i) wf[i] = *(const short8*)(Wb + i*16*64);
#pragma unroll
    for (int mt = 0; mt < 4; ++mt)
#pragma unroll
      for (int nt = 0; nt < 4; ++nt)
        acc[mt][nt] = __builtin_amdgcn_mfma_f32_16x16x32_bf16(af[mt], wf[nt], acc[mt][nt], 0, 0, 0);
    __syncthreads();
  }

  // C/D layout (verified m89/m91): col = lane&15, row = (lane>>4)*4 + r
  const int mbase = row0 + wm*64 + ((lane >> 4) * 4);
  const int nbase = col0 + wn*64 + (lane & 15);
#pragma unroll
  for (int mt = 0; mt < 4; ++mt) {
#pragma unroll
    for (int nt = 0; nt < 4; ++nt) {
#pragma unroll
      for (int r = 0; r < 4; ++r) {
        int row = mbase + mt*16 + r;
        int col = nbase + nt*16;
        float v = acc[mt][nt][r];
        if (EPI == 0) {
          outF[(size_t)row * ldC + col] = v;
        } else if (EPI == 2) {
          if (col < 96) outF[(size_t)row * 96 + col] = v;
          if (col < 64) aux[(size_t)row * 64 + col] = __float2bfloat16(v);
        } else if (EPI == 3) {
          v += biasF[col];
          float sp = (v > 20.0f) ? v : log1pf(__expf(v));
          outF[(size_t)row * ldC + col] = sp;
        } else if (EPI == 4) {
          if (col < DINNER) {
            outH[(size_t)row * DINNER + col] = __float2bfloat16(v);
          } else {
            outF[(size_t)row * DINNER + (col - DINNER)] = v * sigmoidf_(v);  // silu(z), f32
          }
        }
      }
    }
  }
}

// ---------------------------------------------------------------------------
// Depthwise causal conv (k=4) + bias + SiLU.  xi: [ROWS, DINNER] bf16.
// ---------------------------------------------------------------------------
__global__ __launch_bounds__(256)
void conv_silu_k(const __hip_bfloat16* __restrict__ xi,
                 const float* __restrict__ cw,
                 const float* __restrict__ cb,
                 __hip_bfloat16* __restrict__ xcH)
{
  int idx = blockIdx.x * 256 + threadIdx.x;
  if (idx >= ROWS * DINNER) return;
  int d  = idx & (DINNER - 1);
  int t  = (idx >> 11) & (SEQ - 1);
  int bt = idx >> 11;                       // b*SEQ + t
  float acc = cb[d];
#pragma unroll
  for (int i = 0; i < 4; ++i) {
    int tt = t - 3 + i;
    if (tt >= 0) acc += cw[d*4 + i] * bf2f(xi[(size_t)(bt - 3 + i) * DINNER + d]);
  }
  float y = acc * sigmoidf_(acc);
  xcH[idx] = __float2bfloat16(y);
}

// ---------------------------------------------------------------------------
// Selective scan + fused combine. 1 wave/block, 16 channels/block (4 lanes per
// channel, 4 states/lane). Register double-buffered 4-step prefetch.
// grid = BATCH * (DINNER/16) = 256 blocks.
// y = (sum_n h_n C_n + xc*D) * siluz  -> bf16
// ---------------------------------------------------------------------------
__global__ __launch_bounds__(64)
void scan_k(const float* __restrict__ delta,
            const __hip_bfloat16* __restrict__ xcH,
            const float* __restrict__ xdbl,
            const float* __restrict__ zsF,
            const float* __restrict__ alF,
            const float* __restrict__ DF,
            __hip_bfloat16* __restrict__ yH)
{
  const int bid = blockIdx.x;
  const int b   = bid >> 7;                       // /128
  const int ch  = ((bid & 127) << 4) + (threadIdx.x >> 2);
  const int sub = threadIdx.x & 3;                // states n = sub*4..sub*4+3
  float negA[4];
#pragma unroll
  for (int j = 0; j < 4; ++j)
    negA[j] = -__expf(alF[ch * NSTATE + sub*4 + j]);
  const float Dch = DF[ch];

  const size_t rb = (size_t)b * SEQ;
  const float*          dp = delta + rb * DINNER + ch;
  const __hip_bfloat16* xp = xcH   + rb * DINNER + ch;
  const float*          zp = zsF   + rb * DINNER + ch;
  const float*          bp = xdbl  + rb * 96 + 64 + sub*4;
  const float*          cp = xdbl  + rb * 96 + 80 + sub*4;
  __hip_bfloat16*       yp = yH    + rb * DINNER + ch;

  float h0=0.f, h1=0.f, h2=0.f, h3=0.f;
  float  dl[2][4], xv[2][4], zv[2][4];
  float4 Bv[2][4], Cv[2][4];

#pragma unroll
  for (int u = 0; u < 4; ++u) {               // prefetch group 0
    dl[0][u] = dp[(size_t)u * DINNER];
    xv[0][u] = bf2f(xp[(size_t)u * DINNER]);
    zv[0][u] = zp[(size_t)u * DINNER];
    Bv[0][u] = *(const float4*)(bp + (size_t)u * 96);
    Cv[0][u] = *(const float4*)(cp + (size_t)u * 96);
  }

  for (int g = 0; g < SEQ/4; ++g) {
    const int cur = g & 1;
    if (g < SEQ/4 - 1) {
      const int nb = cur ^ 1;
      const int t0 = (g+1)*4;
#pragma unroll
      for (int u = 0; u < 4; ++u) {
        dl[nb][u] = dp[(size_t)(t0+u) * DINNER];
        xv[nb][u] = bf2f(xp[(size_t)(t0+u) * DINNER]);
        zv[nb][u] = zp[(size_t)(t0+u) * DINNER];
        Bv[nb][u] = *(const float4*)(bp + (size_t)(t0+u) * 96);
        Cv[nb][u] = *(const float4*)(cp + (size_t)(t0+u) * 96);
      }
    }
#pragma unroll
    for (int u = 0; u < 4; ++u) {
      float d_ = dl[cur][u];
      float du = d_ * xv[cur][u];
      float4 B4 = Bv[cur][u], C4 = Cv[cur][u];
      float a0 = __expf(d_ * negA[0]);
      float a1 = __expf(d_ * negA[1]);
      float a2 = __expf(d_ * negA[2]);
      float a3 = __expf(d_ * negA[3]);
      h0 = a0*h0 + du*B4.x;
      h1 = a1*h1 + du*B4.y;
      h2 = a2*h2 + du*B4.z;
      h3 = a3*h3 + du*B4.w;
      float p = h0*C4.x + h1*C4.y + h2*C4.z + h3*C4.w;
      p += __shfl_xor(p, 1);
      p += __shfl_xor(p, 2);
      float y = (p + xv[cur][u] * Dch) * zv[cur][u];
      if (sub == 0) yp[(size_t)(g*4+u) * DINNER] = __float2bfloat16(y);
    }
  }
}

// ---------------------------------------------------------------------------
extern "C" void kernel_launch(void* const* d_in, const int* in_sizes, int n_in,
                              void* d_out, int out_size, void* d_ws, size_t ws_size,
                              hipStream_t stream)
{
  float* out = (float*)d_out;   // reference output dtype: float32
  char* ws = (char*)d_ws;
  const size_t MB = 1024*1024;

  // workspace layout (60 MB, liveness-aliased)
  int*            flag    = (int*)            (ws);
  float*          cwF     = (float*)          (ws + 1024);          // 32 KB
  float*          cbF     = (float*)          (ws + 40*1024);       // 8 KB
  float*          dtbF    = (float*)          (ws + 56*1024);       // 8 KB
  float*          alF     = (float*)          (ws + 72*1024);       // 128 KB
  float*          DF      = (float*)          (ws + 208*1024);      // 8 KB
  __hip_bfloat16* xB      = (__hip_bfloat16*) (ws + 1*MB);          // 4 MB  (dead after G1)
  __hip_bfloat16* inpB    = (__hip_bfloat16*) (ws + 5*MB);          // 8 MB  (dead after G1)
  __hip_bfloat16* xiB     = (__hip_bfloat16*) (ws + 13*MB);         // 8 MB  (dead after G2)
  float*          dlt     = (float*)          (ws + 1*MB);          // 16 MB (G4..G5) aliases xB/inpB/xiB[:4]
  __hip_bfloat16* xprojB  = (__hip_bfloat16*) (ws + 21*MB);         // 384 KB
  __hip_bfloat16* dtprojB = (__hip_bfloat16*) (ws + 21*MB + 512*1024); // 256 KB
  __hip_bfloat16* outpB   = (__hip_bfloat16*) (ws + 22*MB);         // 4 MB
  float*          zsF     = (float*)          (ws + 26*MB);         // 16 MB
  __hip_bfloat16* xcH     = (__hip_bfloat16*) (ws + 42*MB);         // 8 MB
  float*          xdbl    = (float*)          (ws + 50*MB);         // 768 KB
  __hip_bfloat16* dtH     = (__hip_bfloat16*) (ws + 51*MB);         // 256 KB
  __hip_bfloat16* yH      = (__hip_bfloat16*) (ws + 52*MB);         // 8 MB -> top 60 MB

  dim3 blk(256);

  // 0) sniff input storage dtype, then canonicalize all inputs
  sniff_k<<<1, 64, 0, stream>>>((const unsigned short*)d_in[0], flag);
  convert_k<<<(in_sizes[0]+255)/256, blk, 0, stream>>>(d_in[0], in_sizes[0], flag, xB, nullptr);
  convert_k<<<(in_sizes[1]+255)/256, blk, 0, stream>>>(d_in[1], in_sizes[1], flag, inpB, nullptr);
  convert_k<<<(in_sizes[2]+255)/256, blk, 0, stream>>>(d_in[2], in_sizes[2], flag, nullptr, cwF);
  convert_k<<<(in_sizes[3]+255)/256, blk, 0, stream>>>(d_in[3], in_sizes[3], flag, nullptr, cbF);
  convert_k<<<(in_sizes[4]+255)/256, blk, 0, stream>>>(d_in[4], in_sizes[4], flag, xprojB, nullptr);
  convert_k<<<(in_sizes[5]+255)/256, blk, 0, stream>>>(d_in[5], in_sizes[5], flag, dtprojB, nullptr);
  convert_k<<<(in_sizes[6]+255)/256, blk, 0, stream>>>(d_in[6], in_sizes[6], flag, nullptr, dtbF);
  convert_k<<<(in_sizes[7]+255)/256, blk, 0, stream>>>(d_in[7], in_sizes[7], flag, nullptr, alF);
  convert_k<<<(in_sizes[8]+255)/256, blk, 0, stream>>>(d_in[8], in_sizes[8], flag, nullptr, DF);
  convert_k<<<(in_sizes[9]+255)/256, blk, 0, stream>>>(d_in[9], in_sizes[9], flag, outpB, nullptr);

  // 1) in_proj: xz = x @ in_proj^T (2048 x 4096 x 1024); split -> xi bf16, silu(z) f32
  gemm_bt<4><<<dim3(4096/128, ROWS/128), blk, 0, stream>>>(
      xB, inpB, ROWS, 2*DINNER, DMODEL, 0, zsF, xiB, nullptr, nullptr);

  // 2) xc = silu(depthwise_conv(xi) + b)
  conv_silu_k<<<(ROWS*DINNER)/256, blk, 0, stream>>>(xiB, cwF, cbF, xcH);

  // 3) x_dbl = xc @ x_proj^T (2048 x 96 x 2048) -> f32 xdbl + bf16 dt copy
  gemm_bt<2><<<dim3(1, ROWS/128), blk, 0, stream>>>(
      xcH, xprojB, ROWS, 96, DINNER, 96, xdbl, nullptr, nullptr, dtH);

  // 4) delta = softplus(dt @ dt_proj^T + dt_b)  (2048 x 2048 x 64) -> f32
  //    (dlt aliases xB/inpB/xiB which are dead by now)
  gemm_bt<3><<<dim3(DINNER/128, ROWS/128), blk, 0, stream>>>(
      dtH, dtprojB, ROWS, DINNER, DTRANK, DINNER, dlt, nullptr, dtbF, nullptr);

  // 5) selective scan + fused (p + xc*D)*silu(z) -> bf16 yH
  scan_k<<<BATCH*(DINNER/16), 64, 0, stream>>>(dlt, xcH, xdbl, zsF, alF, DF, yH);

  // 6) out = y @ out_proj^T (2048 x 1024 x 2048) -> f32 d_out
  gemm_bt<0><<<dim3(DMODEL/128, ROWS/128), blk, 0, stream>>>(
      yH, outpB, ROWS, DMODEL, DINNER, DMODEL, out, nullptr, nullptr, nullptr);
}

// Round 4
// 620.991 us; speedup vs baseline: 1.9062x; 1.9062x over previous
//
#include <hip/hip_runtime.h>
#include <hip/hip_bf16.h>
#include <cstdint>
#include <cstddef>

#define DMODEL 1024
#define DINNER 2048
#define NSTATE 16
#define DTRANK 64
#define BATCH 2
#define SEQ 1024
#define ROWS (BATCH*SEQ)   // 2048 token rows

typedef __attribute__((ext_vector_type(8))) short short8;
typedef __attribute__((ext_vector_type(4))) float f32x4;

__device__ __forceinline__ float bf2f(__hip_bfloat16 h){ return __bfloat162float(h); }
__device__ __forceinline__ float sigmoidf_(float x){ return 1.0f/(1.0f + __expf(-x)); }

__device__ __forceinline__ void gld16(const void* g, void* l){
  __builtin_amdgcn_global_load_lds((const __attribute__((address_space(1))) void*)g,
                                   (__attribute__((address_space(3))) void*)l, 16, 0, 0);
}

// ---------------------------------------------------------------------------
// dtype sniffer (validated R2/R3: picked f32 on f32 data).
// ---------------------------------------------------------------------------
__global__ void sniff_k(const unsigned short* __restrict__ xu, int* __restrict__ flag)
{
  int t = threadIdx.x;           // 64 threads
  int cnt = 0;
  for (int i = t; i < 1024; i += 64) {
    unsigned short u = xu[i];
    int e = (u >> 7) & 0xFF;
    if (e >= 0x70 && e <= 0x86) cnt++;
  }
  for (int o = 32; o; o >>= 1) cnt += __shfl_down(cnt, o);
  if (t == 0) *flag = (cnt >= 768) ? 0 : 1;
}

// canonicalize one tensor: read per flag, write bf16 and/or f32 copies
__global__ __launch_bounds__(256)
void convert_k(const void* __restrict__ src, int n, const int* __restrict__ flag,
               __hip_bfloat16* __restrict__ dB, float* __restrict__ dF)
{
  int i = blockIdx.x * 256 + threadIdx.x;
  if (i >= n) return;
  float v;
  if (*flag) v = ((const float*)src)[i];
  else       v = bf2f(((const __hip_bfloat16*)src)[i]);
  if (dB) dB[i] = __float2bfloat16(v);
  if (dF) dF[i] = v;
}

// ---------------------------------------------------------------------------
// NT GEMM: C[M,N] = A[M,K] (bf16, lda=K) x W[N,K]^T (bf16, ldw=K)
// 128x128 tile, BK=32, 256 threads (4 waves 2x2), mfma_f32_16x16x32_bf16.
// EPI: 0 = store f32 (ldC)                          (out_proj -> f32 d_out)
//      2 = x_dbl split: f32 cols<96 + bf16 cols<64 into aux (dt)
//      3 = softplus(acc + biasF[col]) -> f32 (ldC)  (delta)
//      4 = in_proj split: col<2048 -> bf16 xi (outH); col>=2048 -> silu -> f32 outF
// ---------------------------------------------------------------------------
template<int EPI>
__global__ __launch_bounds__(256)
void gemm_bt(const __hip_bfloat16* __restrict__ A,
             const __hip_bfloat16* __restrict__ W,
             int M, int N, int K, int ldC,
             float* __restrict__ outF,
             __hip_bfloat16* __restrict__ outH,
             const float* __restrict__ biasF,
             __hip_bfloat16* __restrict__ aux)
{
  __shared__ alignas(16) __hip_bfloat16 As[128*32];
  __shared__ alignas(16) __hip_bfloat16 Ws[128*32];
  const int tid  = threadIdx.x;
  const int lane = tid & 63;
  const int wave = tid >> 6;
  const int wm = wave & 1, wn = wave >> 1;
  const int row0 = blockIdx.y * 128;
  const int col0 = blockIdx.x * 128;

  f32x4 acc[4][4] = {};

  const int e0 = tid, e1 = tid + 256;   // 16B-granule ids (512 per tile)

  for (int k0 = 0; k0 < K; k0 += 32) {
    { // A tile: granule e covers row e/4, k-seg e%4 (8 bf16); LDS offset e*16
      int r = e0 >> 2, ks = e0 & 3;
      gld16(A + (size_t)(row0 + r) * K + k0 + ks*8, (char*)As + (size_t)e0*16);
      r = e1 >> 2; ks = e1 & 3;
      gld16(A + (size_t)(row0 + r) * K + k0 + ks*8, (char*)As + (size_t)e1*16);
    }
    { // W tile (clamp row for N<128: keeps addresses in-bounds; masked at store)
      int r = e0 >> 2, ks = e0 & 3;
      int rw = col0 + r; if (rw > N-1) rw = N-1;
      gld16(W + (size_t)rw * K + k0 + ks*8, (char*)Ws + (size_t)e0*16);
      r = e1 >> 2; ks = e1 & 3;
      rw = col0 + r; if (rw > N-1) rw = N-1;
      gld16(W + (size_t)rw * K + k0 + ks*8, (char*)Ws + (size_t)e1*16);
    }
    __syncthreads();   // compiler drains vmcnt before s_barrier

    const char* Ab = (const char*)As + ((wm*64 + (lane & 15)) * 64) + ((lane >> 4) * 16);
    const char* Wb = (const char*)Ws + ((wn*64 + (lane & 15)) * 64) + ((lane >> 4) * 16);
    short8 af[4], wf[4];
#pragma unroll
    for (int i = 0; i < 4; ++i) af[i] = *(const short8*)(Ab + i*16*64);
#pragma unroll
    for (int i = 0; i < 4; ++i) wf[i] = *(const short8*)(Wb + i*16*64);
#pragma unroll
    for (int mt = 0; mt < 4; ++mt)
#pragma unroll
      for (int nt = 0; nt < 4; ++nt)
        acc[mt][nt] = __builtin_amdgcn_mfma_f32_16x16x32_bf16(af[mt], wf[nt], acc[mt][nt], 0, 0, 0);
    __syncthreads();
  }

  // C/D layout (verified m89/m91): col = lane&15, row = (lane>>4)*4 + r
  const int mbase = row0 + wm*64 + ((lane >> 4) * 4);
  const int nbase = col0 + wn*64 + (lane & 15);
#pragma unroll
  for (int mt = 0; mt < 4; ++mt) {
#pragma unroll
    for (int nt = 0; nt < 4; ++nt) {
#pragma unroll
      for (int r = 0; r < 4; ++r) {
        int row = mbase + mt*16 + r;
        int col = nbase + nt*16;
        float v = acc[mt][nt][r];
        if (EPI == 0) {
          outF[(size_t)row * ldC + col] = v;
        } else if (EPI == 2) {
          if (col < 96) outF[(size_t)row * 96 + col] = v;
          if (col < 64) aux[(size_t)row * 64 + col] = __float2bfloat16(v);
        } else if (EPI == 3) {
          v += biasF[col];
          float sp = (v > 20.0f) ? v : log1pf(__expf(v));
          outF[(size_t)row * ldC + col] = sp;
        } else if (EPI == 4) {
          if (col < DINNER) {
            outH[(size_t)row * DINNER + col] = __float2bfloat16(v);
          } else {
            outF[(size_t)row * DINNER + (col - DINNER)] = v * sigmoidf_(v);  // silu(z), f32
          }
        }
      }
    }
  }
}

// ---------------------------------------------------------------------------
// Depthwise causal conv (k=4) + bias + SiLU.  xi: [ROWS, DINNER] bf16.
// ---------------------------------------------------------------------------
__global__ __launch_bounds__(256)
void conv_silu_k(const __hip_bfloat16* __restrict__ xi,
                 const float* __restrict__ cw,
                 const float* __restrict__ cb,
                 __hip_bfloat16* __restrict__ xcH)
{
  int idx = blockIdx.x * 256 + threadIdx.x;
  if (idx >= ROWS * DINNER) return;
  int d  = idx & (DINNER - 1);
  int t  = (idx >> 11) & (SEQ - 1);
  int bt = idx >> 11;                       // b*SEQ + t
  float acc = cb[d];
#pragma unroll
  for (int i = 0; i < 4; ++i) {
    int tt = t - 3 + i;
    if (tt >= 0) acc += cw[d*4 + i] * bf2f(xi[(size_t)(bt - 3 + i) * DINNER + d]);
  }
  float y = acc * sigmoidf_(acc);
  xcH[idx] = __float2bfloat16(y);
}

// ---------------------------------------------------------------------------
// Selective scan + fused combine, v2.
// 256 threads/block = 4 waves; 16 channels/block (4 per wave); 1 state/lane
// (n = lane&15), shfl_xor reduce over 16 lanes. grid = 256 blocks -> 4 waves
// per CU (one per SIMD). Static double-buffered prefetch of 8-step groups —
// ALL buffer indices compile-time constant (R3's dynamic cur=g&1 indexing
// spilled to scratch: VGPR_Count=36, 897us).
// y = (sum_n h_n C_n + xc*D) * siluz  -> bf16
// ---------------------------------------------------------------------------
#define GSTEP 8
__global__ __launch_bounds__(256)
void scan_k(const float* __restrict__ delta,
            const __hip_bfloat16* __restrict__ xcH,
            const float* __restrict__ xdbl,
            const float* __restrict__ zsF,
            const float* __restrict__ alF,
            const float* __restrict__ DF,
            __hip_bfloat16* __restrict__ yH)
{
  const int bid  = blockIdx.x;
  const int b    = bid >> 7;                         // /128
  const int wave = threadIdx.x >> 6;
  const int lane = threadIdx.x & 63;
  const int n    = lane & 15;                        // state index
  const int ch   = ((bid & 127) << 4) + (wave << 2) + (lane >> 4);

  const float negA = -__expf(alF[ch * NSTATE + n]);
  const float Dch  = DF[ch];

  const size_t rb = (size_t)b * SEQ;
  const float*          dp = delta + rb * DINNER + ch;
  const __hip_bfloat16* xp = xcH   + rb * DINNER + ch;
  const float*          zp = zsF   + rb * DINNER + ch;
  const float*          bq = xdbl  + rb * 96 + 64 + n;   // per-lane scalar
  const float*          cq = xdbl  + rb * 96 + 80 + n;
  __hip_bfloat16*       yp = yH    + rb * DINNER + ch;

  float h = 0.f;

  float dA[GSTEP], xA[GSTEP], zA[GSTEP], BA[GSTEP], CA[GSTEP];
  float dB[GSTEP], xB[GSTEP], zB[GSTEP], BB[GSTEP], CB[GSTEP];

#define PF(D_,X_,Z_,B_,C_,T0) \
  _Pragma("unroll") \
  for (int u = 0; u < GSTEP; ++u) { \
    D_[u] = dp[(size_t)((T0)+u) * DINNER]; \
    X_[u] = bf2f(xp[(size_t)((T0)+u) * DINNER]); \
    Z_[u] = zp[(size_t)((T0)+u) * DINNER]; \
    B_[u] = bq[(size_t)((T0)+u) * 96]; \
    C_[u] = cq[(size_t)((T0)+u) * 96]; \
  }

#define STEPS(D_,X_,Z_,B_,C_,T0) \
  _Pragma("unroll") \
  for (int u = 0; u < GSTEP; ++u) { \
    float d_ = D_[u]; \
    float a  = __expf(d_ * negA); \
    h = a * h + (d_ * X_[u]) * B_[u]; \
    float p = h * C_[u]; \
    p += __shfl_xor(p, 1); \
    p += __shfl_xor(p, 2); \
    p += __shfl_xor(p, 4); \
    p += __shfl_xor(p, 8); \
    if (n == 0) { \
      float y = (p + X_[u] * Dch) * Z_[u]; \
      yp[(size_t)((T0)+u) * DINNER] = __float2bfloat16(y); \
    } \
  }

  PF(dA, xA, zA, BA, CA, 0)
  for (int t0 = 0; t0 < SEQ; t0 += 2*GSTEP) {
    PF(dB, xB, zB, BB, CB, t0 + GSTEP)
    STEPS(dA, xA, zA, BA, CA, t0)
    if (t0 + 2*GSTEP < SEQ) { PF(dA, xA, zA, BA, CA, t0 + 2*GSTEP) }
    STEPS(dB, xB, zB, BB, CB, t0 + GSTEP)
  }
#undef PF
#undef STEPS
}

// ---------------------------------------------------------------------------
extern "C" void kernel_launch(void* const* d_in, const int* in_sizes, int n_in,
                              void* d_out, int out_size, void* d_ws, size_t ws_size,
                              hipStream_t stream)
{
  float* out = (float*)d_out;   // reference output dtype: float32
  char* ws = (char*)d_ws;
  const size_t MB = 1024*1024;

  // workspace layout (60 MB, liveness-aliased)
  int*            flag    = (int*)            (ws);
  float*          cwF     = (float*)          (ws + 1024);          // 32 KB
  float*          cbF     = (float*)          (ws + 40*1024);       // 8 KB
  float*          dtbF    = (float*)          (ws + 56*1024);       // 8 KB
  float*          alF     = (float*)          (ws + 72*1024);       // 128 KB
  float*          DF      = (float*)          (ws + 208*1024);      // 8 KB
  __hip_bfloat16* xB      = (__hip_bfloat16*) (ws + 1*MB);          // 4 MB  (dead after G1)
  __hip_bfloat16* inpB    = (__hip_bfloat16*) (ws + 5*MB);          // 8 MB  (dead after G1)
  __hip_bfloat16* xiB     = (__hip_bfloat16*) (ws + 13*MB);         // 8 MB  (dead after G2)
  float*          dlt     = (float*)          (ws + 1*MB);          // 16 MB (G4..G5) aliases xB/inpB/xiB[:4]
  __hip_bfloat16* xprojB  = (__hip_bfloat16*) (ws + 21*MB);         // 384 KB
  __hip_bfloat16* dtprojB = (__hip_bfloat16*) (ws + 21*MB + 512*1024); // 256 KB
  __hip_bfloat16* outpB   = (__hip_bfloat16*) (ws + 22*MB);         // 4 MB
  float*          zsF     = (float*)          (ws + 26*MB);         // 16 MB
  __hip_bfloat16* xcH     = (__hip_bfloat16*) (ws + 42*MB);         // 8 MB
  float*          xdbl    = (float*)          (ws + 50*MB);         // 768 KB
  __hip_bfloat16* dtH     = (__hip_bfloat16*) (ws + 51*MB);         // 256 KB
  __hip_bfloat16* yH      = (__hip_bfloat16*) (ws + 52*MB);         // 8 MB -> top 60 MB

  dim3 blk(256);

  // 0) sniff input storage dtype, then canonicalize all inputs
  sniff_k<<<1, 64, 0, stream>>>((const unsigned short*)d_in[0], flag);
  convert_k<<<(in_sizes[0]+255)/256, blk, 0, stream>>>(d_in[0], in_sizes[0], flag, xB, nullptr);
  convert_k<<<(in_sizes[1]+255)/256, blk, 0, stream>>>(d_in[1], in_sizes[1], flag, inpB, nullptr);
  convert_k<<<(in_sizes[2]+255)/256, blk, 0, stream>>>(d_in[2], in_sizes[2], flag, nullptr, cwF);
  convert_k<<<(in_sizes[3]+255)/256, blk, 0, stream>>>(d_in[3], in_sizes[3], flag, nullptr, cbF);
  convert_k<<<(in_sizes[4]+255)/256, blk, 0, stream>>>(d_in[4], in_sizes[4], flag, xprojB, nullptr);
  convert_k<<<(in_sizes[5]+255)/256, blk, 0, stream>>>(d_in[5], in_sizes[5], flag, dtprojB, nullptr);
  convert_k<<<(in_sizes[6]+255)/256, blk, 0, stream>>>(d_in[6], in_sizes[6], flag, nullptr, dtbF);
  convert_k<<<(in_sizes[7]+255)/256, blk, 0, stream>>>(d_in[7], in_sizes[7], flag, nullptr, alF);
  convert_k<<<(in_sizes[8]+255)/256, blk, 0, stream>>>(d_in[8], in_sizes[8], flag, nullptr, DF);
  convert_k<<<(in_sizes[9]+255)/256, blk, 0, stream>>>(d_in[9], in_sizes[9], flag, outpB, nullptr);

  // 1) in_proj: xz = x @ in_proj^T (2048 x 4096 x 1024); split -> xi bf16, silu(z) f32
  gemm_bt<4><<<dim3(4096/128, ROWS/128), blk, 0, stream>>>(
      xB, inpB, ROWS, 2*DINNER, DMODEL, 0, zsF, xiB, nullptr, nullptr);

  // 2) xc = silu(depthwise_conv(xi) + b)
  conv_silu_k<<<(ROWS*DINNER)/256, blk, 0, stream>>>(xiB, cwF, cbF, xcH);

  // 3) x_dbl = xc @ x_proj^T (2048 x 96 x 2048) -> f32 xdbl + bf16 dt copy
  gemm_bt<2><<<dim3(1, ROWS/128), blk, 0, stream>>>(
      xcH, xprojB, ROWS, 96, DINNER, 96, xdbl, nullptr, nullptr, dtH);

  // 4) delta = softplus(dt @ dt_proj^T + dt_b)  (2048 x 2048 x 64) -> f32
  //    (dlt aliases xB/inpB/xiB which are dead by now)
  gemm_bt<3><<<dim3(DINNER/128, ROWS/128), blk, 0, stream>>>(
      dtH, dtprojB, ROWS, DINNER, DTRANK, DINNER, dlt, nullptr, dtbF, nullptr);

  // 5) selective scan + fused (p + xc*D)*silu(z) -> bf16 yH
  scan_k<<<BATCH*(DINNER/16), 256, 0, stream>>>(dlt, xcH, xdbl, zsF, alF, DF, yH);

  // 6) out = y @ out_proj^T (2048 x 1024 x 2048) -> f32 d_out
  gemm_bt<0><<<dim3(DMODEL/128, ROWS/128), blk, 0, stream>>>(
      yH, outpB, ROWS, DMODEL, DINNER, DMODEL, out, nullptr, nullptr, nullptr);
}

// Round 5
// 541.696 us; speedup vs baseline: 2.1852x; 1.1464x over previous
//
#include <hip/hip_runtime.h>
#include <hip/hip_bf16.h>
#include <cstdint>
#include <cstddef>

#define DMODEL 1024
#define DINNER 2048
#define NSTATE 16
#define DTRANK 64
#define BATCH 2
#define SEQ 1024
#define ROWS (BATCH*SEQ)   // 2048 token rows
#define NCHUNK 8
#define CLEN (SEQ/NCHUNK)  // 128
#define KSPLIT 16          // split-K ways for x_proj GEMM

typedef __attribute__((ext_vector_type(8))) short short8;
typedef __attribute__((ext_vector_type(4))) float f32x4;

__device__ __forceinline__ float bf2f(__hip_bfloat16 h){ return __bfloat162float(h); }
__device__ __forceinline__ float sigmoidf_(float x){ return 1.0f/(1.0f + __expf(-x)); }

__device__ __forceinline__ void gld16(const void* g, void* l){
  __builtin_amdgcn_global_load_lds((const __attribute__((address_space(1))) void*)g,
                                   (__attribute__((address_space(3))) void*)l, 16, 0, 0);
}

// ---------------------------------------------------------------------------
// dtype sniffer (validated R2/R3: picked f32 on f32 data).
// ---------------------------------------------------------------------------
__global__ void sniff_k(const unsigned short* __restrict__ xu, int* __restrict__ flag)
{
  int t = threadIdx.x;           // 64 threads
  int cnt = 0;
  for (int i = t; i < 1024; i += 64) {
    unsigned short u = xu[i];
    int e = (u >> 7) & 0xFF;
    if (e >= 0x70 && e <= 0x86) cnt++;
  }
  for (int o = 32; o; o >>= 1) cnt += __shfl_down(cnt, o);
  if (t == 0) *flag = (cnt >= 768) ? 0 : 1;
}

// canonicalize one tensor: read per flag, write bf16 and/or f32 copies
__global__ __launch_bounds__(256)
void convert_k(const void* __restrict__ src, int n, const int* __restrict__ flag,
               __hip_bfloat16* __restrict__ dB, float* __restrict__ dF)
{
  int i = blockIdx.x * 256 + threadIdx.x;
  if (i >= n) return;
  float v;
  if (*flag) v = ((const float*)src)[i];
  else       v = bf2f(((const __hip_bfloat16*)src)[i]);
  if (dB) dB[i] = __float2bfloat16(v);
  if (dF) dF[i] = v;
}

// ---------------------------------------------------------------------------
// NT GEMM: C[M,N] = A[M,K] (bf16, lda=K) x W[N,K]^T (bf16, ldw=K)
// 128x128 tile, BK=32, 256 threads (4 waves 2x2), mfma_f32_16x16x32_bf16.
// EPI: 0 = store f32 (ldC)                          (out_proj -> f32 d_out)
//      3 = softplus(acc + biasF[col]) -> f32 (ldC)  (delta)
//      4 = in_proj split: col<2048 -> bf16 xi (outH); col>=2048 -> silu -> f32 outF
//      5 = split-K partial: f32 -> outF + blockIdx.z*ROWS*96, cols<96 (x_proj)
// ---------------------------------------------------------------------------
template<int EPI>
__global__ __launch_bounds__(256)
void gemm_bt(const __hip_bfloat16* __restrict__ A,
             const __hip_bfloat16* __restrict__ W,
             int M, int N, int K, int ldC, int kchunk,
             float* __restrict__ outF,
             __hip_bfloat16* __restrict__ outH,
             const float* __restrict__ biasF)
{
  __shared__ alignas(16) __hip_bfloat16 As[128*32];
  __shared__ alignas(16) __hip_bfloat16 Ws[128*32];
  const int tid  = threadIdx.x;
  const int lane = tid & 63;
  const int wave = tid >> 6;
  const int wm = wave & 1, wn = wave >> 1;
  const int row0 = blockIdx.y * 128;
  const int col0 = blockIdx.x * 128;

  f32x4 acc[4][4] = {};

  const int e0 = tid, e1 = tid + 256;   // 16B-granule ids (512 per tile)

  int kbeg = 0, kend = K;
  if (EPI == 5) { kbeg = blockIdx.z * kchunk; kend = kbeg + kchunk; }

  for (int k0 = kbeg; k0 < kend; k0 += 32) {
    { // A tile: granule e covers row e/4, k-seg e%4 (8 bf16); LDS offset e*16
      int r = e0 >> 2, ks = e0 & 3;
      gld16(A + (size_t)(row0 + r) * K + k0 + ks*8, (char*)As + (size_t)e0*16);
      r = e1 >> 2; ks = e1 & 3;
      gld16(A + (size_t)(row0 + r) * K + k0 + ks*8, (char*)As + (size_t)e1*16);
    }
    { // W tile (clamp row for N<128: keeps addresses in-bounds; masked at store)
      int r = e0 >> 2, ks = e0 & 3;
      int rw = col0 + r; if (rw > N-1) rw = N-1;
      gld16(W + (size_t)rw * K + k0 + ks*8, (char*)Ws + (size_t)e0*16);
      r = e1 >> 2; ks = e1 & 3;
      rw = col0 + r; if (rw > N-1) rw = N-1;
      gld16(W + (size_t)rw * K + k0 + ks*8, (char*)Ws + (size_t)e1*16);
    }
    __syncthreads();   // compiler drains vmcnt before s_barrier

    const char* Ab = (const char*)As + ((wm*64 + (lane & 15)) * 64) + ((lane >> 4) * 16);
    const char* Wb = (const char*)Ws + ((wn*64 + (lane & 15)) * 64) + ((lane >> 4) * 16);
    short8 af[4], wf[4];
#pragma unroll
    for (int i = 0; i < 4; ++i) af[i] = *(const short8*)(Ab + i*16*64);
#pragma unroll
    for (int i = 0; i < 4; ++i) wf[i] = *(const short8*)(Wb + i*16*64);
#pragma unroll
    for (int mt = 0; mt < 4; ++mt)
#pragma unroll
      for (int nt = 0; nt < 4; ++nt)
        acc[mt][nt] = __builtin_amdgcn_mfma_f32_16x16x32_bf16(af[mt], wf[nt], acc[mt][nt], 0, 0, 0);
    __syncthreads();
  }

  // C/D layout (verified m89/m91): col = lane&15, row = (lane>>4)*4 + r
  const int mbase = row0 + wm*64 + ((lane >> 4) * 4);
  const int nbase = col0 + wn*64 + (lane & 15);
#pragma unroll
  for (int mt = 0; mt < 4; ++mt) {
#pragma unroll
    for (int nt = 0; nt < 4; ++nt) {
#pragma unroll
      for (int r = 0; r < 4; ++r) {
        int row = mbase + mt*16 + r;
        int col = nbase + nt*16;
        float v = acc[mt][nt][r];
        if (EPI == 0) {
          outF[(size_t)row * ldC + col] = v;
        } else if (EPI == 3) {
          v += biasF[col];
          float sp = (v > 20.0f) ? v : log1pf(__expf(v));
          outF[(size_t)row * ldC + col] = sp;
        } else if (EPI == 4) {
          if (col < DINNER) {
            outH[(size_t)row * DINNER + col] = __float2bfloat16(v);
          } else {
            outF[(size_t)row * DINNER + (col - DINNER)] = v * sigmoidf_(v);  // silu(z), f32
          }
        } else if (EPI == 5) {
          if (col < 96)
            outF[(size_t)blockIdx.z * (ROWS*96) + (size_t)row * 96 + col] = v;
        }
      }
    }
  }
}

// ---------------------------------------------------------------------------
// split-K reduce for x_dbl: sum KSPLIT partials -> f32 xdbl; cols<64 -> bf16 dt
// ---------------------------------------------------------------------------
__global__ __launch_bounds__(256)
void reduce_xdbl_k(const float* __restrict__ part, float* __restrict__ xdbl,
                   __hip_bfloat16* __restrict__ dtH)
{
  int i = blockIdx.x * 256 + threadIdx.x;
  if (i >= ROWS*96) return;
  float s = 0.f;
#pragma unroll
  for (int kc = 0; kc < KSPLIT; ++kc) s += part[(size_t)kc*ROWS*96 + i];
  xdbl[i] = s;
  int row = i / 96, col = i - row*96;
  if (col < 64) dtH[(size_t)row*64 + col] = __float2bfloat16(s);
}

// ---------------------------------------------------------------------------
// Depthwise causal conv (k=4) + bias + SiLU.  xi: [ROWS, DINNER] bf16.
// ---------------------------------------------------------------------------
__global__ __launch_bounds__(256)
void conv_silu_k(const __hip_bfloat16* __restrict__ xi,
                 const float* __restrict__ cw,
                 const float* __restrict__ cb,
                 __hip_bfloat16* __restrict__ xcH)
{
  int idx = blockIdx.x * 256 + threadIdx.x;
  if (idx >= ROWS * DINNER) return;
  int d  = idx & (DINNER - 1);
  int t  = (idx >> 11) & (SEQ - 1);
  int bt = idx >> 11;                       // b*SEQ + t
  float acc = cb[d];
#pragma unroll
  for (int i = 0; i < 4; ++i) {
    int tt = t - 3 + i;
    if (tt >= 0) acc += cw[d*4 + i] * bf2f(xi[(size_t)(bt - 3 + i) * DINNER + d]);
  }
  float y = acc * sigmoidf_(acc);
  xcH[idx] = __float2bfloat16(y);
}

// ---------------------------------------------------------------------------
// Chunked selective scan (R4's 337us scan was latency-bound at 1 block/CU:
// VALUBusy 12%, Occ 11.8%). Linear recurrence => chunk decomposition:
//   pass1 stats_k : per chunk: sum_d (=> chunk product exp(negA*sum_d)) and
//                   local final h from h=0.           grid 2048 = 8 blk/CU
//   pass2 carry_k : 8 sequential fmas -> h_in per chunk (tiny)
//   pass3 emit_k  : chunk scan seeded with h_in, emits y.  grid 2048
// Lane map (all passes): 16 ch/block, 4 ch/wave, n = lane&15.
// ---------------------------------------------------------------------------
#define GSTEP 8

__global__ __launch_bounds__(256)
void stats_k(const float* __restrict__ delta,
             const __hip_bfloat16* __restrict__ xcH,
             const float* __restrict__ xdbl,
             const float* __restrict__ alF,
             float* __restrict__ Hc, float* __restrict__ Sd)
{
  const int bid   = blockIdx.x;              // b*1024 + c*128 + chgrp
  const int b     = bid >> 10;
  const int c     = (bid >> 7) & (NCHUNK-1);
  const int chgrp = bid & 127;
  const int wave  = threadIdx.x >> 6;
  const int lane  = threadIdx.x & 63;
  const int n     = lane & 15;
  const int ch    = (chgrp << 4) + (wave << 2) + (lane >> 4);

  const float negA = -__expf(alF[ch * NSTATE + n]);

  const size_t rb = (size_t)b * SEQ + (size_t)c * CLEN;
  const float*          dp = delta + rb * DINNER + ch;
  const __hip_bfloat16* xp = xcH   + rb * DINNER + ch;
  const float*          bq = xdbl  + rb * 96 + 64 + n;

  float h = 0.f, sd = 0.f;
  float d0[GSTEP], x0[GSTEP], B0[GSTEP];
  float d1[GSTEP], x1[GSTEP], B1[GSTEP];

#define PF1(D_,X_,B_,T0) \
  _Pragma("unroll") \
  for (int u = 0; u < GSTEP; ++u) { \
    D_[u] = dp[(size_t)((T0)+u) * DINNER]; \
    X_[u] = bf2f(xp[(size_t)((T0)+u) * DINNER]); \
    B_[u] = bq[(size_t)((T0)+u) * 96]; \
  }
#define ST1(D_,X_,B_) \
  _Pragma("unroll") \
  for (int u = 0; u < GSTEP; ++u) { \
    float d_ = D_[u]; \
    sd += d_; \
    float a = __expf(d_ * negA); \
    h = a * h + (d_ * X_[u]) * B_[u]; \
  }

  PF1(d0, x0, B0, 0)
  for (int t0 = 0; t0 < CLEN; t0 += 2*GSTEP) {
    PF1(d1, x1, B1, t0 + GSTEP)
    ST1(d0, x0, B0)
    if (t0 + 2*GSTEP < CLEN) { PF1(d0, x0, B0, t0 + 2*GSTEP) }
    ST1(d1, x1, B1)
  }
#undef PF1
#undef ST1

  const size_t bc = (size_t)(b*NCHUNK + c);
  Hc[(bc*DINNER + ch)*NSTATE + n] = h;
  if (n == 0) Sd[bc*DINNER + ch] = sd;
}

__global__ __launch_bounds__(256)
void carry_k(const float* __restrict__ Hc, const float* __restrict__ Sd,
             const float* __restrict__ alF, float* __restrict__ hin)
{
  int i = blockIdx.x * 256 + threadIdx.x;       // BATCH*DINNER*NSTATE = 65536
  int n  = i & (NSTATE-1);
  int ch = (i >> 4) & (DINNER-1);
  int b  = i >> 15;
  float negA = -__expf(alF[ch * NSTATE + n]);
  float h = 0.f;
#pragma unroll
  for (int c = 0; c < NCHUNK; ++c) {
    size_t bc = (size_t)(b*NCHUNK + c);
    hin[(bc*DINNER + ch)*NSTATE + n] = h;
    float P = __expf(negA * Sd[bc*DINNER + ch]);
    h = P * h + Hc[(bc*DINNER + ch)*NSTATE + n];
  }
}

__global__ __launch_bounds__(256)
void emit_k(const float* __restrict__ delta,
            const __hip_bfloat16* __restrict__ xcH,
            const float* __restrict__ xdbl,
            const float* __restrict__ zsF,
            const float* __restrict__ alF,
            const float* __restrict__ DF,
            const float* __restrict__ hin,
            __hip_bfloat16* __restrict__ yH)
{
  const int bid   = blockIdx.x;
  const int b     = bid >> 10;
  const int c     = (bid >> 7) & (NCHUNK-1);
  const int chgrp = bid & 127;
  const int wave  = threadIdx.x >> 6;
  const int lane  = threadIdx.x & 63;
  const int n     = lane & 15;
  const int ch    = (chgrp << 4) + (wave << 2) + (lane >> 4);

  const float negA = -__expf(alF[ch * NSTATE + n]);
  const float Dch  = DF[ch];

  const size_t rb = (size_t)b * SEQ + (size_t)c * CLEN;
  const float*          dp = delta + rb * DINNER + ch;
  const __hip_bfloat16* xp = xcH   + rb * DINNER + ch;
  const float*          zp = zsF   + rb * DINNER + ch;
  const float*          bq = xdbl  + rb * 96 + 64 + n;
  const float*          cq = xdbl  + rb * 96 + 80 + n;
  __hip_bfloat16*       yp = yH    + rb * DINNER + ch;

  float h = hin[((size_t)(b*NCHUNK + c)*DINNER + ch)*NSTATE + n];

  float d0[GSTEP], x0[GSTEP], z0[GSTEP], B0[GSTEP], C0[GSTEP];
  float d1[GSTEP], x1[GSTEP], z1[GSTEP], B1[GSTEP], C1[GSTEP];

#define PF(D_,X_,Z_,B_,C_,T0) \
  _Pragma("unroll") \
  for (int u = 0; u < GSTEP; ++u) { \
    D_[u] = dp[(size_t)((T0)+u) * DINNER]; \
    X_[u] = bf2f(xp[(size_t)((T0)+u) * DINNER]); \
    Z_[u] = zp[(size_t)((T0)+u) * DINNER]; \
    B_[u] = bq[(size_t)((T0)+u) * 96]; \
    C_[u] = cq[(size_t)((T0)+u) * 96]; \
  }
#define STEPS(D_,X_,Z_,B_,C_,T0) \
  _Pragma("unroll") \
  for (int u = 0; u < GSTEP; ++u) { \
    float d_ = D_[u]; \
    float a  = __expf(d_ * negA); \
    h = a * h + (d_ * X_[u]) * B_[u]; \
    float p = h * C_[u]; \
    p += __shfl_xor(p, 1); \
    p += __shfl_xor(p, 2); \
    p += __shfl_xor(p, 4); \
    p += __shfl_xor(p, 8); \
    if (n == 0) { \
      float y = (p + X_[u] * Dch) * Z_[u]; \
      yp[(size_t)((T0)+u) * DINNER] = __float2bfloat16(y); \
    } \
  }

  PF(d0, x0, z0, B0, C0, 0)
  for (int t0 = 0; t0 < CLEN; t0 += 2*GSTEP) {
    PF(d1, x1, z1, B1, C1, t0 + GSTEP)
    STEPS(d0, x0, z0, B0, C0, t0)
    if (t0 + 2*GSTEP < CLEN) { PF(d0, x0, z0, B0, C0, t0 + 2*GSTEP) }
    STEPS(d1, x1, z1, B1, C1, t0 + GSTEP)
  }
#undef PF
#undef STEPS
}

// ---------------------------------------------------------------------------
extern "C" void kernel_launch(void* const* d_in, const int* in_sizes, int n_in,
                              void* d_out, int out_size, void* d_ws, size_t ws_size,
                              hipStream_t stream)
{
  float* out = (float*)d_out;   // reference output dtype: float32
  char* ws = (char*)d_ws;
  const size_t MB = 1024*1024;

  // workspace layout (64.2 MB, liveness-aliased)
  int*            flag    = (int*)            (ws);
  float*          cwF     = (float*)          (ws + 1024);          // 32 KB
  float*          cbF     = (float*)          (ws + 40*1024);       // 8 KB
  float*          dtbF    = (float*)          (ws + 56*1024);       // 8 KB
  float*          alF     = (float*)          (ws + 72*1024);       // 128 KB
  float*          DF      = (float*)          (ws + 208*1024);      // 8 KB
  __hip_bfloat16* xB      = (__hip_bfloat16*) (ws + 1*MB);          // 4 MB  (dead after G1)
  __hip_bfloat16* inpB    = (__hip_bfloat16*) (ws + 5*MB);          // 8 MB  (dead after G1)
  __hip_bfloat16* xiB     = (__hip_bfloat16*) (ws + 13*MB);         // 8 MB  (dead after conv)
  float*          part    = (float*)          (ws + 1*MB);          // 12 MB (G3->reduce) aliases xB/inpB
  float*          dlt     = (float*)          (ws + 1*MB);          // 16 MB (G4->emit) aliases part/xiB[:4MB]
  __hip_bfloat16* xprojB  = (__hip_bfloat16*) (ws + 21*MB);         // 384 KB
  __hip_bfloat16* dtprojB = (__hip_bfloat16*) (ws + 21*MB + 512*1024); // 256 KB
  __hip_bfloat16* outpB   = (__hip_bfloat16*) (ws + 22*MB);         // 4 MB
  float*          zsF     = (float*)          (ws + 26*MB);         // 16 MB
  __hip_bfloat16* xcH     = (__hip_bfloat16*) (ws + 42*MB);         // 8 MB
  float*          xdbl    = (float*)          (ws + 50*MB);         // 768 KB
  __hip_bfloat16* dtH     = (__hip_bfloat16*) (ws + 51*MB);         // 256 KB
  __hip_bfloat16* yH      = (__hip_bfloat16*) (ws + 52*MB);         // 8 MB
  float*          Hc      = (float*)          (ws + 60*MB);         // 2 MB
  float*          hin     = (float*)          (ws + 62*MB);         // 2 MB
  float*          Sd      = (float*)          (ws + 64*MB);         // 128 KB -> top 64.2 MB

  dim3 blk(256);

  // 0) sniff input storage dtype, then canonicalize all inputs
  sniff_k<<<1, 64, 0, stream>>>((const unsigned short*)d_in[0], flag);
  convert_k<<<(in_sizes[0]+255)/256, blk, 0, stream>>>(d_in[0], in_sizes[0], flag, xB, nullptr);
  convert_k<<<(in_sizes[1]+255)/256, blk, 0, stream>>>(d_in[1], in_sizes[1], flag, inpB, nullptr);
  convert_k<<<(in_sizes[2]+255)/256, blk, 0, stream>>>(d_in[2], in_sizes[2], flag, nullptr, cwF);
  convert_k<<<(in_sizes[3]+255)/256, blk, 0, stream>>>(d_in[3], in_sizes[3], flag, nullptr, cbF);
  convert_k<<<(in_sizes[4]+255)/256, blk, 0, stream>>>(d_in[4], in_sizes[4], flag, xprojB, nullptr);
  convert_k<<<(in_sizes[5]+255)/256, blk, 0, stream>>>(d_in[5], in_sizes[5], flag, dtprojB, nullptr);
  convert_k<<<(in_sizes[6]+255)/256, blk, 0, stream>>>(d_in[6], in_sizes[6], flag, nullptr, dtbF);
  convert_k<<<(in_sizes[7]+255)/256, blk, 0, stream>>>(d_in[7], in_sizes[7], flag, nullptr, alF);
  convert_k<<<(in_sizes[8]+255)/256, blk, 0, stream>>>(d_in[8], in_sizes[8], flag, nullptr, DF);
  convert_k<<<(in_sizes[9]+255)/256, blk, 0, stream>>>(d_in[9], in_sizes[9], flag, outpB, nullptr);

  // 1) in_proj: xz = x @ in_proj^T (2048 x 4096 x 1024); split -> xi bf16, silu(z) f32
  gemm_bt<4><<<dim3(4096/128, ROWS/128), blk, 0, stream>>>(
      xB, inpB, ROWS, 2*DINNER, DMODEL, 0, 0, zsF, xiB, nullptr);

  // 2) xc = silu(depthwise_conv(xi) + b)
  conv_silu_k<<<(ROWS*DINNER)/256, blk, 0, stream>>>(xiB, cwF, cbF, xcH);

  // 3) x_dbl partials: xc @ x_proj^T (2048 x 96 x 2048), 16-way split-K
  //    (R4 ran this on a 16-block grid = 6% of CUs)
  gemm_bt<5><<<dim3(1, ROWS/128, KSPLIT), blk, 0, stream>>>(
      xcH, xprojB, ROWS, 96, DINNER, 0, DINNER/KSPLIT, part, nullptr, nullptr);
  reduce_xdbl_k<<<(ROWS*96+255)/256, blk, 0, stream>>>(part, xdbl, dtH);

  // 4) delta = softplus(dt @ dt_proj^T + dt_b)  (2048 x 2048 x 64) -> f32
  gemm_bt<3><<<dim3(DINNER/128, ROWS/128), blk, 0, stream>>>(
      dtH, dtprojB, ROWS, DINNER, DTRANK, DINNER, 0, dlt, nullptr, dtbF);

  // 5) chunked selective scan + fused (p + xc*D)*silu(z) -> bf16 yH
  stats_k<<<BATCH*NCHUNK*128, blk, 0, stream>>>(dlt, xcH, xdbl, alF, Hc, Sd);
  carry_k<<<(BATCH*DINNER*NSTATE)/256, blk, 0, stream>>>(Hc, Sd, alF, hin);
  emit_k<<<BATCH*NCHUNK*128, blk, 0, stream>>>(dlt, xcH, xdbl, zsF, alF, DF, hin, yH);

  // 6) out = y @ out_proj^T (2048 x 1024 x 2048) -> f32 d_out
  gemm_bt<0><<<dim3(DMODEL/128, ROWS/128), blk, 0, stream>>>(
      yH, outpB, ROWS, DMODEL, DINNER, DMODEL, 0, out, nullptr, nullptr);
}

// Round 6
// 334.543 us; speedup vs baseline: 3.5384x; 1.6192x over previous
//
#include <hip/hip_runtime.h>
#include <hip/hip_bf16.h>
#include <cstdint>
#include <cstddef>

#define DMODEL 1024
#define DINNER 2048
#define NSTATE 16
#define DTRANK 64
#define BATCH 2
#define SEQ 1024
#define ROWS (BATCH*SEQ)   // 2048 token rows
#define NCHUNK 16
#define CLEN (SEQ/NCHUNK)  // 64
#define KSPLIT 16          // split-K ways for x_proj GEMM

typedef __attribute__((ext_vector_type(8))) short short8;
typedef __attribute__((ext_vector_type(4))) float f32x4;

__device__ __forceinline__ float bf2f(__hip_bfloat16 h){ return __bfloat162float(h); }
__device__ __forceinline__ float sigmoidf_(float x){ return 1.0f/(1.0f + __expf(-x)); }

__device__ __forceinline__ void gld16(const void* g, void* l){
  __builtin_amdgcn_global_load_lds((const __attribute__((address_space(1))) void*)g,
                                   (__attribute__((address_space(3))) void*)l, 16, 0, 0);
}

// ---------------------------------------------------------------------------
// dtype sniffer (validated R2..R5: picked f32 on f32 data).
// ---------------------------------------------------------------------------
__global__ void sniff_k(const unsigned short* __restrict__ xu, int* __restrict__ flag)
{
  int t = threadIdx.x;           // 64 threads
  int cnt = 0;
  for (int i = t; i < 1024; i += 64) {
    unsigned short u = xu[i];
    int e = (u >> 7) & 0xFF;
    if (e >= 0x70 && e <= 0x86) cnt++;
  }
  for (int o = 32; o; o >>= 1) cnt += __shfl_down(cnt, o);
  if (t == 0) *flag = (cnt >= 768) ? 0 : 1;
}

// ---------------------------------------------------------------------------
// Fused canonicalizer: all 10 inputs in ONE launch (R5 used 10 launches ->
// ~1+ us dispatch overhead each on a serialized stream).
// Compile-time segment table; if-chain keeps each branch's pointers static.
// ---------------------------------------------------------------------------
struct CvtArgs {
  const void *s0,*s1,*s2,*s3,*s4,*s5,*s6,*s7,*s8,*s9;
  __hip_bfloat16 *xB,*inpB,*xprojB,*dtprojB,*outpB;
  float *cwF,*cbF,*dtbF,*alF,*DF;
  const int* flag;
};
#define CVT_S0 2097152
#define CVT_C1 2097152      // +S1 4194304
#define CVT_C2 6291456      // +S2 8192
#define CVT_C3 6299648      // +S3 2048
#define CVT_C4 6301696      // +S4 196608
#define CVT_C5 6498304      // +S5 131072
#define CVT_C6 6629376      // +S6 2048
#define CVT_C7 6631424      // +S7 32768
#define CVT_C8 6664192      // +S8 2048
#define CVT_C9 6666240      // +S9 2097152
#define CVT_TOT 8763392     // = 256 * 34232

__device__ __forceinline__ float cvt_read(const void* s, int j, int fl){
  return fl ? ((const float*)s)[j] : bf2f(((const __hip_bfloat16*)s)[j]);
}

__global__ __launch_bounds__(256)
void convert_all_k(CvtArgs a)
{
  int i = blockIdx.x * 256 + threadIdx.x;
  if (i >= CVT_TOT) return;
  const int fl = *a.flag;
  if (i < CVT_C1)      a.xB[i]                = __float2bfloat16(cvt_read(a.s0, i, fl));
  else if (i < CVT_C2) a.inpB[i-CVT_C1]       = __float2bfloat16(cvt_read(a.s1, i-CVT_C1, fl));
  else if (i < CVT_C3) a.cwF[i-CVT_C2]        = cvt_read(a.s2, i-CVT_C2, fl);
  else if (i < CVT_C4) a.cbF[i-CVT_C3]        = cvt_read(a.s3, i-CVT_C3, fl);
  else if (i < CVT_C5) a.xprojB[i-CVT_C4]     = __float2bfloat16(cvt_read(a.s4, i-CVT_C4, fl));
  else if (i < CVT_C6) a.dtprojB[i-CVT_C5]    = __float2bfloat16(cvt_read(a.s5, i-CVT_C5, fl));
  else if (i < CVT_C7) a.dtbF[i-CVT_C6]       = cvt_read(a.s6, i-CVT_C6, fl);
  else if (i < CVT_C8) a.alF[i-CVT_C7]        = cvt_read(a.s7, i-CVT_C7, fl);
  else if (i < CVT_C9) a.DF[i-CVT_C8]         = cvt_read(a.s8, i-CVT_C8, fl);
  else                 a.outpB[i-CVT_C9]      = __float2bfloat16(cvt_read(a.s9, i-CVT_C9, fl));
}

// ---------------------------------------------------------------------------
// NT GEMM: C[M,N] = A[M,K] (bf16, lda=K) x W[N,K]^T (bf16, ldw=K)
// 128x128 tile, BK=32, 256 threads (4 waves 2x2), mfma_f32_16x16x32_bf16.
// EPI: 0 = store f32 (ldC)
//      3 = softplus(acc + biasF[col]) -> f32 (ldC)  (delta; branch-free fast
//          softplus — R5's log1pf epilogue at 1 wave/SIMD cost 110us)
//      4 = in_proj split: col<2048 -> bf16 xi (outH); col>=2048 -> silu -> f32 outF
//      5 = split-K partial: f32 -> outF + z*ROWS*96, cols<96 (x_proj)
//      6 = split-K partial: f32 -> q[z] (out_proj; 4 fragmented 8MB buffers)
// ---------------------------------------------------------------------------
template<int EPI>
__global__ __launch_bounds__(256)
void gemm_bt(const __hip_bfloat16* __restrict__ A,
             const __hip_bfloat16* __restrict__ W,
             int M, int N, int K, int ldC, int kchunk,
             float* __restrict__ outF,
             __hip_bfloat16* __restrict__ outH,
             const float* __restrict__ biasF,
             float* __restrict__ q0, float* __restrict__ q1,
             float* __restrict__ q2, float* __restrict__ q3)
{
  __shared__ alignas(16) __hip_bfloat16 As[128*32];
  __shared__ alignas(16) __hip_bfloat16 Ws[128*32];
  const int tid  = threadIdx.x;
  const int lane = tid & 63;
  const int wave = tid >> 6;
  const int wm = wave & 1, wn = wave >> 1;
  const int row0 = blockIdx.y * 128;
  const int col0 = blockIdx.x * 128;

  f32x4 acc[4][4] = {};

  const int e0 = tid, e1 = tid + 256;   // 16B-granule ids (512 per tile)

  int kbeg = 0, kend = K;
  if (EPI == 5 || EPI == 6) { kbeg = blockIdx.z * kchunk; kend = kbeg + kchunk; }

  for (int k0 = kbeg; k0 < kend; k0 += 32) {
    { // A tile: granule e covers row e/4, k-seg e%4 (8 bf16); LDS offset e*16
      int r = e0 >> 2, ks = e0 & 3;
      gld16(A + (size_t)(row0 + r) * K + k0 + ks*8, (char*)As + (size_t)e0*16);
      r = e1 >> 2; ks = e1 & 3;
      gld16(A + (size_t)(row0 + r) * K + k0 + ks*8, (char*)As + (size_t)e1*16);
    }
    { // W tile (clamp row for N<128: keeps addresses in-bounds; masked at store)
      int r = e0 >> 2, ks = e0 & 3;
      int rw = col0 + r; if (rw > N-1) rw = N-1;
      gld16(W + (size_t)rw * K + k0 + ks*8, (char*)Ws + (size_t)e0*16);
      r = e1 >> 2; ks = e1 & 3;
      rw = col0 + r; if (rw > N-1) rw = N-1;
      gld16(W + (size_t)rw * K + k0 + ks*8, (char*)Ws + (size_t)e1*16);
    }
    __syncthreads();   // compiler drains vmcnt before s_barrier

    const char* Ab = (const char*)As + ((wm*64 + (lane & 15)) * 64) + ((lane >> 4) * 16);
    const char* Wb = (const char*)Ws + ((wn*64 + (lane & 15)) * 64) + ((lane >> 4) * 16);
    short8 af[4], wf[4];
#pragma unroll
    for (int i = 0; i < 4; ++i) af[i] = *(const short8*)(Ab + i*16*64);
#pragma unroll
    for (int i = 0; i < 4; ++i) wf[i] = *(const short8*)(Wb + i*16*64);
#pragma unroll
    for (int mt = 0; mt < 4; ++mt)
#pragma unroll
      for (int nt = 0; nt < 4; ++nt)
        acc[mt][nt] = __builtin_amdgcn_mfma_f32_16x16x32_bf16(af[mt], wf[nt], acc[mt][nt], 0, 0, 0);
    __syncthreads();
  }

  // C/D layout (verified m89/m91): col = lane&15, row = (lane>>4)*4 + r
  const int mbase = row0 + wm*64 + ((lane >> 4) * 4);
  const int nbase = col0 + wn*64 + (lane & 15);

  float bv[4];
  if (EPI == 3) {      // hoist bias loads out of the epilogue loops
#pragma unroll
    for (int nt = 0; nt < 4; ++nt) bv[nt] = biasF[nbase + nt*16];
  }
  float* qz = nullptr;
  if (EPI == 6) qz = (blockIdx.z == 0) ? q0 : (blockIdx.z == 1) ? q1
                   : (blockIdx.z == 2) ? q2 : q3;

#pragma unroll
  for (int mt = 0; mt < 4; ++mt) {
#pragma unroll
    for (int nt = 0; nt < 4; ++nt) {
#pragma unroll
      for (int r = 0; r < 4; ++r) {
        int row = mbase + mt*16 + r;
        int col = nbase + nt*16;
        float v = acc[mt][nt][r];
        if (EPI == 0) {
          outF[(size_t)row * ldC + col] = v;
        } else if (EPI == 3) {
          v += bv[nt];
          // softplus(v) = max(v,0) + log(1 + exp(-|v|)); arg in (1,2] -> no
          // cancellation, pure HW v_exp/v_log, branch-free.
          float sp = fmaxf(v, 0.0f) + __logf(1.0f + __expf(-fabsf(v)));
          outF[(size_t)row * ldC + col] = sp;
        } else if (EPI == 4) {
          if (col < DINNER) {
            outH[(size_t)row * DINNER + col] = __float2bfloat16(v);
          } else {
            outF[(size_t)row * DINNER + (col - DINNER)] = v * sigmoidf_(v);  // silu(z), f32
          }
        } else if (EPI == 5) {
          if (col < 96)
            outF[(size_t)blockIdx.z * (ROWS*96) + (size_t)row * 96 + col] = v;
        } else if (EPI == 6) {
          qz[(size_t)row * DMODEL + col] = v;
        }
      }
    }
  }
}

// ---------------------------------------------------------------------------
// split-K reduce for x_dbl: sum KSPLIT partials -> f32 xdbl; cols<64 -> bf16 dt
// ---------------------------------------------------------------------------
__global__ __launch_bounds__(256)
void reduce_xdbl_k(const float* __restrict__ part, float* __restrict__ xdbl,
                   __hip_bfloat16* __restrict__ dtH)
{
  int i = blockIdx.x * 256 + threadIdx.x;
  if (i >= ROWS*96) return;
  float s = 0.f;
#pragma unroll
  for (int kc = 0; kc < KSPLIT; ++kc) s += part[(size_t)kc*ROWS*96 + i];
  xdbl[i] = s;
  int row = i / 96, col = i - row*96;
  if (col < 64) dtH[(size_t)row*64 + col] = __float2bfloat16(s);
}

// split-K reduce for out_proj: out = q0+q1+q2+q3 (f32)
__global__ __launch_bounds__(256)
void reduce_out_k(const float* __restrict__ q0, const float* __restrict__ q1,
                  const float* __restrict__ q2, const float* __restrict__ q3,
                  float* __restrict__ out)
{
  int i = blockIdx.x * 256 + threadIdx.x;
  if (i >= ROWS*DMODEL) return;
  out[i] = (q0[i] + q1[i]) + (q2[i] + q3[i]);
}

// ---------------------------------------------------------------------------
// Depthwise causal conv (k=4) + bias + SiLU.  xi: [ROWS, DINNER] bf16.
// ---------------------------------------------------------------------------
__global__ __launch_bounds__(256)
void conv_silu_k(const __hip_bfloat16* __restrict__ xi,
                 const float* __restrict__ cw,
                 const float* __restrict__ cb,
                 __hip_bfloat16* __restrict__ xcH)
{
  int idx = blockIdx.x * 256 + threadIdx.x;
  if (idx >= ROWS * DINNER) return;
  int d  = idx & (DINNER - 1);
  int t  = (idx >> 11) & (SEQ - 1);
  int bt = idx >> 11;                       // b*SEQ + t
  float acc = cb[d];
#pragma unroll
  for (int i = 0; i < 4; ++i) {
    int tt = t - 3 + i;
    if (tt >= 0) acc += cw[d*4 + i] * bf2f(xi[(size_t)(bt - 3 + i) * DINNER + d]);
  }
  float y = acc * sigmoidf_(acc);
  xcH[idx] = __float2bfloat16(y);
}

// ---------------------------------------------------------------------------
// Chunked selective scan (R5 validated). NCHUNK=16 now: grid 4096 blocks =
// 16 blk/CU for stats/emit (more TLP for the latency-bound passes).
// Lane map: 16 ch/block, 4 ch/wave, n = lane&15.
// ---------------------------------------------------------------------------
#define GSTEP 8

__global__ __launch_bounds__(256)
void stats_k(const float* __restrict__ delta,
             const __hip_bfloat16* __restrict__ xcH,
             const float* __restrict__ xdbl,
             const float* __restrict__ alF,
             float* __restrict__ Hc, float* __restrict__ Sd)
{
  const int bid   = blockIdx.x;              // b*2048 + c*128 + chgrp
  const int b     = bid >> 11;
  const int c     = (bid >> 7) & (NCHUNK-1);
  const int chgrp = bid & 127;
  const int wave  = threadIdx.x >> 6;
  const int lane  = threadIdx.x & 63;
  const int n     = lane & 15;
  const int ch    = (chgrp << 4) + (wave << 2) + (lane >> 4);

  const float negA = -__expf(alF[ch * NSTATE + n]);

  const size_t rb = (size_t)b * SEQ + (size_t)c * CLEN;
  const float*          dp = delta + rb * DINNER + ch;
  const __hip_bfloat16* xp = xcH   + rb * DINNER + ch;
  const float*          bq = xdbl  + rb * 96 + 64 + n;

  float h = 0.f, sd = 0.f;
  float d0[GSTEP], x0[GSTEP], B0[GSTEP];
  float d1[GSTEP], x1[GSTEP], B1[GSTEP];

#define PF1(D_,X_,B_,T0) \
  _Pragma("unroll") \
  for (int u = 0; u < GSTEP; ++u) { \
    D_[u] = dp[(size_t)((T0)+u) * DINNER]; \
    X_[u] = bf2f(xp[(size_t)((T0)+u) * DINNER]); \
    B_[u] = bq[(size_t)((T0)+u) * 96]; \
  }
#define ST1(D_,X_,B_) \
  _Pragma("unroll") \
  for (int u = 0; u < GSTEP; ++u) { \
    float d_ = D_[u]; \
    sd += d_; \
    float a = __expf(d_ * negA); \
    h = a * h + (d_ * X_[u]) * B_[u]; \
  }

  PF1(d0, x0, B0, 0)
  for (int t0 = 0; t0 < CLEN; t0 += 2*GSTEP) {
    PF1(d1, x1, B1, t0 + GSTEP)
    ST1(d0, x0, B0)
    if (t0 + 2*GSTEP < CLEN) { PF1(d0, x0, B0, t0 + 2*GSTEP) }
    ST1(d1, x1, B1)
  }
#undef PF1
#undef ST1

  const size_t bc = (size_t)(b*NCHUNK + c);
  Hc[(bc*DINNER + ch)*NSTATE + n] = h;
  if (n == 0) Sd[bc*DINNER + ch] = sd;
}

__global__ __launch_bounds__(256)
void carry_k(const float* __restrict__ Hc, const float* __restrict__ Sd,
             const float* __restrict__ alF, float* __restrict__ hin)
{
  int i = blockIdx.x * 256 + threadIdx.x;       // BATCH*DINNER*NSTATE = 65536
  int n  = i & (NSTATE-1);
  int ch = (i >> 4) & (DINNER-1);
  int b  = i >> 15;
  float negA = -__expf(alF[ch * NSTATE + n]);
  float h = 0.f;
#pragma unroll
  for (int c = 0; c < NCHUNK; ++c) {
    size_t bc = (size_t)(b*NCHUNK + c);
    hin[(bc*DINNER + ch)*NSTATE + n] = h;
    float P = __expf(negA * Sd[bc*DINNER + ch]);
    h = P * h + Hc[(bc*DINNER + ch)*NSTATE + n];
  }
}

__global__ __launch_bounds__(256)
void emit_k(const float* __restrict__ delta,
            const __hip_bfloat16* __restrict__ xcH,
            const float* __restrict__ xdbl,
            const float* __restrict__ zsF,
            const float* __restrict__ alF,
            const float* __restrict__ DF,
            const float* __restrict__ hin,
            __hip_bfloat16* __restrict__ yH)
{
  const int bid   = blockIdx.x;
  const int b     = bid >> 11;
  const int c     = (bid >> 7) & (NCHUNK-1);
  const int chgrp = bid & 127;
  const int wave  = threadIdx.x >> 6;
  const int lane  = threadIdx.x & 63;
  const int n     = lane & 15;
  const int ch    = (chgrp << 4) + (wave << 2) + (lane >> 4);

  const float negA = -__expf(alF[ch * NSTATE + n]);
  const float Dch  = DF[ch];

  const size_t rb = (size_t)b * SEQ + (size_t)c * CLEN;
  const float*          dp = delta + rb * DINNER + ch;
  const __hip_bfloat16* xp = xcH   + rb * DINNER + ch;
  const float*          zp = zsF   + rb * DINNER + ch;
  const float*          bq = xdbl  + rb * 96 + 64 + n;
  const float*          cq = xdbl  + rb * 96 + 80 + n;
  __hip_bfloat16*       yp = yH    + rb * DINNER + ch;

  float h = hin[((size_t)(b*NCHUNK + c)*DINNER + ch)*NSTATE + n];

  float d0[GSTEP], x0[GSTEP], z0[GSTEP], B0[GSTEP], C0[GSTEP];
  float d1[GSTEP], x1[GSTEP], z1[GSTEP], B1[GSTEP], C1[GSTEP];

#define PF(D_,X_,Z_,B_,C_,T0) \
  _Pragma("unroll") \
  for (int u = 0; u < GSTEP; ++u) { \
    D_[u] = dp[(size_t)((T0)+u) * DINNER]; \
    X_[u] = bf2f(xp[(size_t)((T0)+u) * DINNER]); \
    Z_[u] = zp[(size_t)((T0)+u) * DINNER]; \
    B_[u] = bq[(size_t)((T0)+u) * 96]; \
    C_[u] = cq[(size_t)((T0)+u) * 96]; \
  }
#define STEPS(D_,X_,Z_,B_,C_,T0) \
  _Pragma("unroll") \
  for (int u = 0; u < GSTEP; ++u) { \
    float d_ = D_[u]; \
    float a  = __expf(d_ * negA); \
    h = a * h + (d_ * X_[u]) * B_[u]; \
    float p = h * C_[u]; \
    p += __shfl_xor(p, 1); \
    p += __shfl_xor(p, 2); \
    p += __shfl_xor(p, 4); \
    p += __shfl_xor(p, 8); \
    if (n == 0) { \
      float y = (p + X_[u] * Dch) * Z_[u]; \
      yp[(size_t)((T0)+u) * DINNER] = __float2bfloat16(y); \
    } \
  }

  PF(d0, x0, z0, B0, C0, 0)
  for (int t0 = 0; t0 < CLEN; t0 += 2*GSTEP) {
    PF(d1, x1, z1, B1, C1, t0 + GSTEP)
    STEPS(d0, x0, z0, B0, C0, t0)
    if (t0 + 2*GSTEP < CLEN) { PF(d0, x0, z0, B0, C0, t0 + 2*GSTEP) }
    STEPS(d1, x1, z1, B1, C1, t0 + GSTEP)
  }
#undef PF
#undef STEPS
}

// ---------------------------------------------------------------------------
extern "C" void kernel_launch(void* const* d_in, const int* in_sizes, int n_in,
                              void* d_out, int out_size, void* d_ws, size_t ws_size,
                              hipStream_t stream)
{
  float* out = (float*)d_out;   // reference output dtype: float32
  char* ws = (char*)d_ws;
  const size_t MB = 1024*1024;

  // workspace layout (68 MB, liveness-aliased)
  int*            flag    = (int*)            (ws);
  float*          cwF     = (float*)          (ws + 1024);          // 32 KB
  float*          cbF     = (float*)          (ws + 40*1024);       // 8 KB
  float*          dtbF    = (float*)          (ws + 56*1024);       // 8 KB
  float*          alF     = (float*)          (ws + 72*1024);       // 128 KB
  float*          DF      = (float*)          (ws + 208*1024);      // 8 KB
  float*          Sd      = (float*)          (ws + 256*1024);      // 256 KB (scan stats)
  __hip_bfloat16* xB      = (__hip_bfloat16*) (ws + 1*MB);          // 4 MB  (dead after G1)
  __hip_bfloat16* inpB    = (__hip_bfloat16*) (ws + 5*MB);          // 8 MB  (dead after G1)
  __hip_bfloat16* xiB     = (__hip_bfloat16*) (ws + 13*MB);         // 8 MB  (dead after conv)
  float*          part    = (float*)          (ws + 1*MB);          // 12 MB (G3->reduce) aliases xB/inpB
  float*          dlt     = (float*)          (ws + 1*MB);          // 16 MB (G4->emit) aliases part/xiB[:4MB]
  __hip_bfloat16* xprojB  = (__hip_bfloat16*) (ws + 21*MB);         // 384 KB
  __hip_bfloat16* dtprojB = (__hip_bfloat16*) (ws + 21*MB + 512*1024); // 256 KB
  __hip_bfloat16* outpB   = (__hip_bfloat16*) (ws + 22*MB);         // 4 MB
  float*          zsF     = (float*)          (ws + 26*MB);         // 16 MB (dead after emit)
  __hip_bfloat16* xcH     = (__hip_bfloat16*) (ws + 42*MB);         // 8 MB  (dead after emit)
  float*          xdbl    = (float*)          (ws + 50*MB);         // 768 KB (dead after emit)
  __hip_bfloat16* dtH     = (__hip_bfloat16*) (ws + 51*MB);         // 256 KB
  __hip_bfloat16* yH      = (__hip_bfloat16*) (ws + 52*MB);         // 8 MB  (live into out_proj)
  float*          Hc      = (float*)          (ws + 60*MB);         // 4 MB
  float*          hin     = (float*)          (ws + 64*MB);         // 4 MB -> top 68 MB
  // out_proj split-K partials (8 MB each), in regions dead after emit_k:
  float*          q0      = (float*)          (ws + 26*MB);         // zsF
  float*          q1      = (float*)          (ws + 34*MB);         // zsF hi
  float*          q2      = (float*)          (ws + 42*MB);         // xcH+xdbl
  float*          q3      = (float*)          (ws + 1*MB);          // dlt

  dim3 blk(256);

  // 0) sniff input storage dtype, then canonicalize all inputs (1 launch)
  sniff_k<<<1, 64, 0, stream>>>((const unsigned short*)d_in[0], flag);
  CvtArgs ca = { d_in[0], d_in[1], d_in[2], d_in[3], d_in[4],
                 d_in[5], d_in[6], d_in[7], d_in[8], d_in[9],
                 xB, inpB, xprojB, dtprojB, outpB,
                 cwF, cbF, dtbF, alF, DF, flag };
  convert_all_k<<<CVT_TOT/256, blk, 0, stream>>>(ca);

  // 1) in_proj: xz = x @ in_proj^T (2048 x 4096 x 1024); split -> xi bf16, silu(z) f32
  gemm_bt<4><<<dim3(4096/128, ROWS/128), blk, 0, stream>>>(
      xB, inpB, ROWS, 2*DINNER, DMODEL, 0, 0, zsF, xiB, nullptr,
      nullptr, nullptr, nullptr, nullptr);

  // 2) xc = silu(depthwise_conv(xi) + b)
  conv_silu_k<<<(ROWS*DINNER)/256, blk, 0, stream>>>(xiB, cwF, cbF, xcH);

  // 3) x_dbl partials: xc @ x_proj^T (2048 x 96 x 2048), 16-way split-K
  gemm_bt<5><<<dim3(1, ROWS/128, KSPLIT), blk, 0, stream>>>(
      xcH, xprojB, ROWS, 96, DINNER, 0, DINNER/KSPLIT, part, nullptr, nullptr,
      nullptr, nullptr, nullptr, nullptr);
  reduce_xdbl_k<<<(ROWS*96+255)/256, blk, 0, stream>>>(part, xdbl, dtH);

  // 4) delta = softplus(dt @ dt_proj^T + dt_b)  (2048 x 2048 x 64) -> f32
  gemm_bt<3><<<dim3(DINNER/128, ROWS/128), blk, 0, stream>>>(
      dtH, dtprojB, ROWS, DINNER, DTRANK, DINNER, 0, dlt, nullptr, dtbF,
      nullptr, nullptr, nullptr, nullptr);

  // 5) chunked selective scan + fused (p + xc*D)*silu(z) -> bf16 yH
  stats_k<<<BATCH*NCHUNK*128, blk, 0, stream>>>(dlt, xcH, xdbl, alF, Hc, Sd);
  carry_k<<<(BATCH*DINNER*NSTATE)/256, blk, 0, stream>>>(Hc, Sd, alF, hin);
  emit_k<<<BATCH*NCHUNK*128, blk, 0, stream>>>(dlt, xcH, xdbl, zsF, alF, DF, hin, yH);

  // 6) out_proj split-K=4: y @ out_proj^T (2048 x 1024 x 2048) -> 4 partials -> f32 d_out
  //    (R5 ran this on 128 blocks = half the GPU idle)
  gemm_bt<6><<<dim3(DMODEL/128, ROWS/128, 4), blk, 0, stream>>>(
      yH, outpB, ROWS, DMODEL, DINNER, 0, DINNER/4, nullptr, nullptr, nullptr,
      q0, q1, q2, q3);
  reduce_out_k<<<(ROWS*DMODEL+255)/256, blk, 0, stream>>>(q0, q1, q2, q3, out);
}

// Round 7
// 268.055 us; speedup vs baseline: 4.4160x; 1.2480x over previous
//
#include <hip/hip_runtime.h>
#include <hip/hip_bf16.h>
#include <cstdint>
#include <cstddef>

#define DMODEL 1024
#define DINNER 2048
#define NSTATE 16
#define DTRANK 64
#define BATCH 2
#define SEQ 1024
#define ROWS (BATCH*SEQ)   // 2048 token rows
#define NCHUNK 16
#define CLEN (SEQ/NCHUNK)  // 64
#define KSPLIT 16          // split-K ways for x_proj GEMM

typedef __attribute__((ext_vector_type(8))) short short8;
typedef __attribute__((ext_vector_type(4))) float f32x4;

__device__ __forceinline__ float bf2f(__hip_bfloat16 h){ return __bfloat162float(h); }
__device__ __forceinline__ float sigmoidf_(float x){ return 1.0f/(1.0f + __expf(-x)); }

__device__ __forceinline__ void gld16(const void* g, void* l){
  __builtin_amdgcn_global_load_lds((const __attribute__((address_space(1))) void*)g,
                                   (__attribute__((address_space(3))) void*)l, 16, 0, 0);
}

// ---------------------------------------------------------------------------
// dtype sniffer (validated R2..R6: picked f32 on f32 data).
// ---------------------------------------------------------------------------
__global__ void sniff_k(const unsigned short* __restrict__ xu, int* __restrict__ flag)
{
  int t = threadIdx.x;           // 64 threads
  int cnt = 0;
  for (int i = t; i < 1024; i += 64) {
    unsigned short u = xu[i];
    int e = (u >> 7) & 0xFF;
    if (e >= 0x70 && e <= 0x86) cnt++;
  }
  for (int o = 32; o; o >>= 1) cnt += __shfl_down(cnt, o);
  if (t == 0) *flag = (cnt >= 768) ? 0 : 1;
}

// ---------------------------------------------------------------------------
// Fused canonicalizer: all 10 inputs in ONE launch.
// ---------------------------------------------------------------------------
struct CvtArgs {
  const void *s0,*s1,*s2,*s3,*s4,*s5,*s6,*s7,*s8,*s9;
  __hip_bfloat16 *xB,*inpB,*xprojB,*dtprojB,*outpB;
  float *cwF,*cbF,*dtbF,*alF,*DF;
  const int* flag;
};
#define CVT_C1 2097152
#define CVT_C2 6291456
#define CVT_C3 6299648
#define CVT_C4 6301696
#define CVT_C5 6498304
#define CVT_C6 6629376
#define CVT_C7 6631424
#define CVT_C8 6664192
#define CVT_C9 6666240
#define CVT_TOT 8763392

__device__ __forceinline__ float cvt_read(const void* s, int j, int fl){
  return fl ? ((const float*)s)[j] : bf2f(((const __hip_bfloat16*)s)[j]);
}

__global__ __launch_bounds__(256)
void convert_all_k(CvtArgs a)
{
  int i = blockIdx.x * 256 + threadIdx.x;
  if (i >= CVT_TOT) return;
  const int fl = *a.flag;
  if (i < CVT_C1)      a.xB[i]                = __float2bfloat16(cvt_read(a.s0, i, fl));
  else if (i < CVT_C2) a.inpB[i-CVT_C1]       = __float2bfloat16(cvt_read(a.s1, i-CVT_C1, fl));
  else if (i < CVT_C3) a.cwF[i-CVT_C2]        = cvt_read(a.s2, i-CVT_C2, fl);
  else if (i < CVT_C4) a.cbF[i-CVT_C3]        = cvt_read(a.s3, i-CVT_C3, fl);
  else if (i < CVT_C5) a.xprojB[i-CVT_C4]     = __float2bfloat16(cvt_read(a.s4, i-CVT_C4, fl));
  else if (i < CVT_C6) a.dtprojB[i-CVT_C5]    = __float2bfloat16(cvt_read(a.s5, i-CVT_C5, fl));
  else if (i < CVT_C7) a.dtbF[i-CVT_C6]       = cvt_read(a.s6, i-CVT_C6, fl);
  else if (i < CVT_C8) a.alF[i-CVT_C7]        = cvt_read(a.s7, i-CVT_C7, fl);
  else if (i < CVT_C9) a.DF[i-CVT_C8]         = cvt_read(a.s8, i-CVT_C8, fl);
  else                 a.outpB[i-CVT_C9]      = __float2bfloat16(cvt_read(a.s9, i-CVT_C9, fl));
}

// ---------------------------------------------------------------------------
// NT GEMM (as R6): 128x128 tile, BK=32, mfma_f32_16x16x32_bf16.
// ---------------------------------------------------------------------------
template<int EPI>
__global__ __launch_bounds__(256)
void gemm_bt(const __hip_bfloat16* __restrict__ A,
             const __hip_bfloat16* __restrict__ W,
             int M, int N, int K, int ldC, int kchunk,
             float* __restrict__ outF,
             __hip_bfloat16* __restrict__ outH,
             const float* __restrict__ biasF,
             float* __restrict__ q0, float* __restrict__ q1,
             float* __restrict__ q2, float* __restrict__ q3)
{
  __shared__ alignas(16) __hip_bfloat16 As[128*32];
  __shared__ alignas(16) __hip_bfloat16 Ws[128*32];
  const int tid  = threadIdx.x;
  const int lane = tid & 63;
  const int wave = tid >> 6;
  const int wm = wave & 1, wn = wave >> 1;
  const int row0 = blockIdx.y * 128;
  const int col0 = blockIdx.x * 128;

  f32x4 acc[4][4] = {};

  const int e0 = tid, e1 = tid + 256;

  int kbeg = 0, kend = K;
  if (EPI == 5 || EPI == 6) { kbeg = blockIdx.z * kchunk; kend = kbeg + kchunk; }

  for (int k0 = kbeg; k0 < kend; k0 += 32) {
    {
      int r = e0 >> 2, ks = e0 & 3;
      gld16(A + (size_t)(row0 + r) * K + k0 + ks*8, (char*)As + (size_t)e0*16);
      r = e1 >> 2; ks = e1 & 3;
      gld16(A + (size_t)(row0 + r) * K + k0 + ks*8, (char*)As + (size_t)e1*16);
    }
    {
      int r = e0 >> 2, ks = e0 & 3;
      int rw = col0 + r; if (rw > N-1) rw = N-1;
      gld16(W + (size_t)rw * K + k0 + ks*8, (char*)Ws + (size_t)e0*16);
      r = e1 >> 2; ks = e1 & 3;
      rw = col0 + r; if (rw > N-1) rw = N-1;
      gld16(W + (size_t)rw * K + k0 + ks*8, (char*)Ws + (size_t)e1*16);
    }
    __syncthreads();

    const char* Ab = (const char*)As + ((wm*64 + (lane & 15)) * 64) + ((lane >> 4) * 16);
    const char* Wb = (const char*)Ws + ((wn*64 + (lane & 15)) * 64) + ((lane >> 4) * 16);
    short8 af[4], wf[4];
#pragma unroll
    for (int i = 0; i < 4; ++i) af[i] = *(const short8*)(Ab + i*16*64);
#pragma unroll
    for (int i = 0; i < 4; ++i) wf[i] = *(const short8*)(Wb + i*16*64);
#pragma unroll
    for (int mt = 0; mt < 4; ++mt)
#pragma unroll
      for (int nt = 0; nt < 4; ++nt)
        acc[mt][nt] = __builtin_amdgcn_mfma_f32_16x16x32_bf16(af[mt], wf[nt], acc[mt][nt], 0, 0, 0);
    __syncthreads();
  }

  const int mbase = row0 + wm*64 + ((lane >> 4) * 4);
  const int nbase = col0 + wn*64 + (lane & 15);

  float bv[4];
  if (EPI == 3) {
#pragma unroll
    for (int nt = 0; nt < 4; ++nt) bv[nt] = biasF[nbase + nt*16];
  }
  float* qz = nullptr;
  if (EPI == 6) qz = (blockIdx.z == 0) ? q0 : (blockIdx.z == 1) ? q1
                   : (blockIdx.z == 2) ? q2 : q3;

#pragma unroll
  for (int mt = 0; mt < 4; ++mt) {
#pragma unroll
    for (int nt = 0; nt < 4; ++nt) {
#pragma unroll
      for (int r = 0; r < 4; ++r) {
        int row = mbase + mt*16 + r;
        int col = nbase + nt*16;
        float v = acc[mt][nt][r];
        if (EPI == 0) {
          outF[(size_t)row * ldC + col] = v;
        } else if (EPI == 3) {
          v += bv[nt];
          float sp = fmaxf(v, 0.0f) + __logf(1.0f + __expf(-fabsf(v)));
          outF[(size_t)row * ldC + col] = sp;
        } else if (EPI == 4) {
          if (col < DINNER) {
            outH[(size_t)row * DINNER + col] = __float2bfloat16(v);
          } else {
            outF[(size_t)row * DINNER + (col - DINNER)] = v * sigmoidf_(v);
          }
        } else if (EPI == 5) {
          if (col < 96)
            outF[(size_t)blockIdx.z * (ROWS*96) + (size_t)row * 96 + col] = v;
        } else if (EPI == 6) {
          qz[(size_t)row * DMODEL + col] = v;
        }
      }
    }
  }
}

// ---------------------------------------------------------------------------
__global__ __launch_bounds__(256)
void reduce_xdbl_k(const float* __restrict__ part, float* __restrict__ xdbl,
                   __hip_bfloat16* __restrict__ dtH)
{
  int i = blockIdx.x * 256 + threadIdx.x;
  if (i >= ROWS*96) return;
  float s = 0.f;
#pragma unroll
  for (int kc = 0; kc < KSPLIT; ++kc) s += part[(size_t)kc*ROWS*96 + i];
  xdbl[i] = s;
  int row = i / 96, col = i - row*96;
  if (col < 64) dtH[(size_t)row*64 + col] = __float2bfloat16(s);
}

__global__ __launch_bounds__(256)
void reduce_out_k(const float* __restrict__ q0, const float* __restrict__ q1,
                  const float* __restrict__ q2, const float* __restrict__ q3,
                  float* __restrict__ out)
{
  int i = blockIdx.x * 256 + threadIdx.x;
  if (i >= ROWS*DMODEL) return;
  out[i] = (q0[i] + q1[i]) + (q2[i] + q3[i]);
}

// ---------------------------------------------------------------------------
__global__ __launch_bounds__(256)
void conv_silu_k(const __hip_bfloat16* __restrict__ xi,
                 const float* __restrict__ cw,
                 const float* __restrict__ cb,
                 __hip_bfloat16* __restrict__ xcH)
{
  int idx = blockIdx.x * 256 + threadIdx.x;
  if (idx >= ROWS * DINNER) return;
  int d  = idx & (DINNER - 1);
  int t  = (idx >> 11) & (SEQ - 1);
  int bt = idx >> 11;
  float acc = cb[d];
#pragma unroll
  for (int i = 0; i < 4; ++i) {
    int tt = t - 3 + i;
    if (tt >= 0) acc += cw[d*4 + i] * bf2f(xi[(size_t)(bt - 3 + i) * DINNER + d]);
  }
  float y = acc * sigmoidf_(acc);
  xcH[idx] = __float2bfloat16(y);
}

// ---------------------------------------------------------------------------
// Chunked selective scan, v3 lane layout (R6's 16-lane/ch layout spent 64
// LDS-pipe shfl ops per channel-step and 16x-redundant B/C global loads):
//   4 lanes/channel, 4 states/lane (sub = lane&3), 16 ch/wave, 64 ch/block,
//   grid = BATCH*NCHUNK*(DINNER/64) = 1024 blocks.
//   B/C are channel-independent -> staged ONCE per block into LDS, read back
//   as broadcast ds_read_b128 (conflict-free). Reduction over 16 states =
//   4 in-register fmas + 2 shfl_xor.
// ---------------------------------------------------------------------------
#define GSTEP 8

__global__ __launch_bounds__(256)
void stats_k(const float* __restrict__ delta,
             const __hip_bfloat16* __restrict__ xcH,
             const float* __restrict__ xdbl,
             const float* __restrict__ alF,
             float* __restrict__ Hc, float* __restrict__ Sd)
{
  __shared__ alignas(16) float Bs[CLEN*16];     // 4 KB
  const int bid  = blockIdx.x;                  // b*512 + c*32 + cg
  const int b    = bid >> 9;
  const int c    = (bid >> 5) & (NCHUNK-1);
  const int cg   = bid & 31;
  const int tid  = threadIdx.x;
  const int lane = tid & 63;
  const int wave = tid >> 6;
  const int sub  = lane & 3;                    // states n = sub*4..sub*4+3
  const int ch   = (cg << 6) + (wave << 4) + (lane >> 2);

  const size_t rb = (size_t)b * SEQ + (size_t)c * CLEN;

  for (int i = tid; i < CLEN*16; i += 256) {    // stage B
    int t = i >> 4, j = i & 15;
    Bs[i] = xdbl[(rb + t)*96 + 64 + j];
  }
  __syncthreads();

  float negA[4];
#pragma unroll
  for (int j = 0; j < 4; ++j) negA[j] = -__expf(alF[ch*NSTATE + sub*4 + j]);

  const float*          dp = delta + rb * DINNER + ch;
  const __hip_bfloat16* xp = xcH   + rb * DINNER + ch;

  float h0=0.f,h1=0.f,h2=0.f,h3=0.f, sd=0.f;
  float d0[GSTEP], x0[GSTEP], d1[GSTEP], x1[GSTEP];

#define PF1(D_,X_,T0) \
  _Pragma("unroll") \
  for (int u = 0; u < GSTEP; ++u) { \
    D_[u] = dp[(size_t)((T0)+u) * DINNER]; \
    X_[u] = bf2f(xp[(size_t)((T0)+u) * DINNER]); \
  }
#define ST1(D_,X_,T0) \
  _Pragma("unroll") \
  for (int u = 0; u < GSTEP; ++u) { \
    float d_ = D_[u]; \
    sd += d_; \
    float du = d_ * X_[u]; \
    f32x4 B4 = *(const f32x4*)&Bs[((T0)+u)*16 + sub*4]; \
    h0 = __expf(d_*negA[0])*h0 + du*B4.x; \
    h1 = __expf(d_*negA[1])*h1 + du*B4.y; \
    h2 = __expf(d_*negA[2])*h2 + du*B4.z; \
    h3 = __expf(d_*negA[3])*h3 + du*B4.w; \
  }

  PF1(d0, x0, 0)
  for (int t0 = 0; t0 < CLEN; t0 += 2*GSTEP) {
    PF1(d1, x1, t0 + GSTEP)
    ST1(d0, x0, t0)
    if (t0 + 2*GSTEP < CLEN) { PF1(d0, x0, t0 + 2*GSTEP) }
    ST1(d1, x1, t0 + GSTEP)
  }
#undef PF1
#undef ST1

  const size_t bc = (size_t)(b*NCHUNK + c);
  f32x4 hv = { h0, h1, h2, h3 };
  *(f32x4*)&Hc[(bc*DINNER + ch)*NSTATE + sub*4] = hv;
  if (sub == 0) Sd[bc*DINNER + ch] = sd;
}

__global__ __launch_bounds__(256)
void carry_k(const float* __restrict__ Hc, const float* __restrict__ Sd,
             const float* __restrict__ alF, float* __restrict__ hin)
{
  int i = blockIdx.x * 256 + threadIdx.x;       // BATCH*DINNER*NSTATE = 65536
  int n  = i & (NSTATE-1);
  int ch = (i >> 4) & (DINNER-1);
  int b  = i >> 15;
  float negA = -__expf(alF[ch * NSTATE + n]);
  float h = 0.f;
#pragma unroll
  for (int c = 0; c < NCHUNK; ++c) {
    size_t bc = (size_t)(b*NCHUNK + c);
    hin[(bc*DINNER + ch)*NSTATE + n] = h;
    float P = __expf(negA * Sd[bc*DINNER + ch]);
    h = P * h + Hc[(bc*DINNER + ch)*NSTATE + n];
  }
}

__global__ __launch_bounds__(256)
void emit_k(const float* __restrict__ delta,
            const __hip_bfloat16* __restrict__ xcH,
            const float* __restrict__ xdbl,
            const float* __restrict__ zsF,
            const float* __restrict__ alF,
            const float* __restrict__ DF,
            const float* __restrict__ hin,
            __hip_bfloat16* __restrict__ yH)
{
  __shared__ alignas(16) float BCs[CLEN*32];    // 8 KB: [t][0:16)=B, [16:32)=C
  const int bid  = blockIdx.x;
  const int b    = bid >> 9;
  const int c    = (bid >> 5) & (NCHUNK-1);
  const int cg   = bid & 31;
  const int tid  = threadIdx.x;
  const int lane = tid & 63;
  const int wave = tid >> 6;
  const int sub  = lane & 3;
  const int ch   = (cg << 6) + (wave << 4) + (lane >> 2);

  const size_t rb = (size_t)b * SEQ + (size_t)c * CLEN;

  for (int i = tid; i < CLEN*32; i += 256) {    // stage B and C
    int t = i >> 5, j = i & 31;
    BCs[i] = xdbl[(rb + t)*96 + 64 + j];
  }
  __syncthreads();

  float negA[4];
#pragma unroll
  for (int j = 0; j < 4; ++j) negA[j] = -__expf(alF[ch*NSTATE + sub*4 + j]);
  const float Dch = DF[ch];

  const float*          dp = delta + rb * DINNER + ch;
  const __hip_bfloat16* xp = xcH   + rb * DINNER + ch;
  const float*          zp = zsF   + rb * DINNER + ch;
  __hip_bfloat16*       yp = yH    + rb * DINNER + ch;

  f32x4 hv = *(const f32x4*)&hin[((size_t)(b*NCHUNK + c)*DINNER + ch)*NSTATE + sub*4];
  float h0=hv.x, h1=hv.y, h2=hv.z, h3=hv.w;

  float d0[GSTEP], x0[GSTEP], z0[GSTEP], d1[GSTEP], x1[GSTEP], z1[GSTEP];

#define PF(D_,X_,Z_,T0) \
  _Pragma("unroll") \
  for (int u = 0; u < GSTEP; ++u) { \
    D_[u] = dp[(size_t)((T0)+u) * DINNER]; \
    X_[u] = bf2f(xp[(size_t)((T0)+u) * DINNER]); \
    Z_[u] = zp[(size_t)((T0)+u) * DINNER]; \
  }
#define STEPS(D_,X_,Z_,T0) \
  _Pragma("unroll") \
  for (int u = 0; u < GSTEP; ++u) { \
    float d_ = D_[u]; \
    float du = d_ * X_[u]; \
    f32x4 B4 = *(const f32x4*)&BCs[((T0)+u)*32 + sub*4]; \
    f32x4 C4 = *(const f32x4*)&BCs[((T0)+u)*32 + 16 + sub*4]; \
    h0 = __expf(d_*negA[0])*h0 + du*B4.x; \
    h1 = __expf(d_*negA[1])*h1 + du*B4.y; \
    h2 = __expf(d_*negA[2])*h2 + du*B4.z; \
    h3 = __expf(d_*negA[3])*h3 + du*B4.w; \
    float p = h0*C4.x + h1*C4.y + h2*C4.z + h3*C4.w; \
    p += __shfl_xor(p, 1); \
    p += __shfl_xor(p, 2); \
    if (sub == 0) { \
      float y = (p + X_[u] * Dch) * Z_[u]; \
      yp[(size_t)((T0)+u) * DINNER] = __float2bfloat16(y); \
    } \
  }

  PF(d0, x0, z0, 0)
  for (int t0 = 0; t0 < CLEN; t0 += 2*GSTEP) {
    PF(d1, x1, z1, t0 + GSTEP)
    STEPS(d0, x0, z0, t0)
    if (t0 + 2*GSTEP < CLEN) { PF(d0, x0, z0, t0 + 2*GSTEP) }
    STEPS(d1, x1, z1, t0 + GSTEP)
  }
#undef PF
#undef STEPS
}

// ---------------------------------------------------------------------------
extern "C" void kernel_launch(void* const* d_in, const int* in_sizes, int n_in,
                              void* d_out, int out_size, void* d_ws, size_t ws_size,
                              hipStream_t stream)
{
  float* out = (float*)d_out;   // reference output dtype: float32
  char* ws = (char*)d_ws;
  const size_t MB = 1024*1024;

  // workspace layout (68 MB, liveness-aliased)
  int*            flag    = (int*)            (ws);
  float*          cwF     = (float*)          (ws + 1024);
  float*          cbF     = (float*)          (ws + 40*1024);
  float*          dtbF    = (float*)          (ws + 56*1024);
  float*          alF     = (float*)          (ws + 72*1024);
  float*          DF      = (float*)          (ws + 208*1024);
  float*          Sd      = (float*)          (ws + 256*1024);      // 256 KB
  __hip_bfloat16* xB      = (__hip_bfloat16*) (ws + 1*MB);          // 4 MB  (dead after G1)
  __hip_bfloat16* inpB    = (__hip_bfloat16*) (ws + 5*MB);          // 8 MB  (dead after G1)
  __hip_bfloat16* xiB     = (__hip_bfloat16*) (ws + 13*MB);         // 8 MB  (dead after conv)
  float*          part    = (float*)          (ws + 1*MB);          // 12 MB aliases xB/inpB
  float*          dlt     = (float*)          (ws + 1*MB);          // 16 MB aliases part/xiB[:4MB]
  __hip_bfloat16* xprojB  = (__hip_bfloat16*) (ws + 21*MB);
  __hip_bfloat16* dtprojB = (__hip_bfloat16*) (ws + 21*MB + 512*1024);
  __hip_bfloat16* outpB   = (__hip_bfloat16*) (ws + 22*MB);         // 4 MB
  float*          zsF     = (float*)          (ws + 26*MB);         // 16 MB (dead after emit)
  __hip_bfloat16* xcH     = (__hip_bfloat16*) (ws + 42*MB);         // 8 MB  (dead after emit)
  float*          xdbl    = (float*)          (ws + 50*MB);         // 768 KB (dead after emit)
  __hip_bfloat16* dtH     = (__hip_bfloat16*) (ws + 51*MB);         // 256 KB
  __hip_bfloat16* yH      = (__hip_bfloat16*) (ws + 52*MB);         // 8 MB  (live into out_proj)
  float*          Hc      = (float*)          (ws + 60*MB);         // 4 MB
  float*          hin     = (float*)          (ws + 64*MB);         // 4 MB -> top 68 MB
  float*          q0      = (float*)          (ws + 26*MB);         // zsF (dead)
  float*          q1      = (float*)          (ws + 34*MB);
  float*          q2      = (float*)          (ws + 42*MB);         // xcH+xdbl (dead)
  float*          q3      = (float*)          (ws + 1*MB);          // dlt (dead)

  dim3 blk(256);

  // 0) sniff + canonicalize
  sniff_k<<<1, 64, 0, stream>>>((const unsigned short*)d_in[0], flag);
  CvtArgs ca = { d_in[0], d_in[1], d_in[2], d_in[3], d_in[4],
                 d_in[5], d_in[6], d_in[7], d_in[8], d_in[9],
                 xB, inpB, xprojB, dtprojB, outpB,
                 cwF, cbF, dtbF, alF, DF, flag };
  convert_all_k<<<CVT_TOT/256, blk, 0, stream>>>(ca);

  // 1) in_proj: split -> xi bf16, silu(z) f32
  gemm_bt<4><<<dim3(4096/128, ROWS/128), blk, 0, stream>>>(
      xB, inpB, ROWS, 2*DINNER, DMODEL, 0, 0, zsF, xiB, nullptr,
      nullptr, nullptr, nullptr, nullptr);

  // 2) xc = silu(depthwise_conv(xi) + b)
  conv_silu_k<<<(ROWS*DINNER)/256, blk, 0, stream>>>(xiB, cwF, cbF, xcH);

  // 3) x_dbl: 16-way split-K + reduce
  gemm_bt<5><<<dim3(1, ROWS/128, KSPLIT), blk, 0, stream>>>(
      xcH, xprojB, ROWS, 96, DINNER, 0, DINNER/KSPLIT, part, nullptr, nullptr,
      nullptr, nullptr, nullptr, nullptr);
  reduce_xdbl_k<<<(ROWS*96+255)/256, blk, 0, stream>>>(part, xdbl, dtH);

  // 4) delta = softplus(dt @ dt_proj^T + dt_b)
  gemm_bt<3><<<dim3(DINNER/128, ROWS/128), blk, 0, stream>>>(
      dtH, dtprojB, ROWS, DINNER, DTRANK, DINNER, 0, dlt, nullptr, dtbF,
      nullptr, nullptr, nullptr, nullptr);

  // 5) chunked selective scan (4-lane/ch layout) + fused combine -> bf16 yH
  stats_k<<<BATCH*NCHUNK*32, blk, 0, stream>>>(dlt, xcH, xdbl, alF, Hc, Sd);
  carry_k<<<(BATCH*DINNER*NSTATE)/256, blk, 0, stream>>>(Hc, Sd, alF, hin);
  emit_k<<<BATCH*NCHUNK*32, blk, 0, stream>>>(dlt, xcH, xdbl, zsF, alF, DF, hin, yH);

  // 6) out_proj split-K=4 + reduce -> f32 d_out
  gemm_bt<6><<<dim3(DMODEL/128, ROWS/128, 4), blk, 0, stream>>>(
      yH, outpB, ROWS, DMODEL, DINNER, 0, DINNER/4, nullptr, nullptr, nullptr,
      q0, q1, q2, q3);
  reduce_out_k<<<(ROWS*DMODEL+255)/256, blk, 0, stream>>>(q0, q1, q2, q3, out);
}